// Round 1
// 511.660 us; speedup vs baseline: 1.0740x; 1.0740x over previous
//
#include <hip/hip_runtime.h>

// MOTCAT_Surv R11. R10 passed (absmax 0.0156, 549 us); screen2 is the whale (170 us,
// MfmaUtil 8%, VALUBusy 53%, 2.1e7 LDS bank-conflict cycles). This round rewrites
// screen2 only: (a) XOR-swizzled 16B-granule B tile staged via global_load_lds with
// inverse-swizzled global source (linear LDS dest), killing the 8-way read conflicts
// and the staging VGPR round-trip; (b) double-buffered Bs -> 1 barrier/tile;
// (c) packed uint sort keys (fp32 monotone key, low 11 bits = in-quarter col) ->
// half the insert VALU + half the merge shuffles; float shadow threshold keeps the
// per-value pre-check at one compare. Screening perturbation 2^-11 rel << bf16 input
// noise; stageD fp64 rescore of all 32 candidates unchanged. Everything else = R10.

typedef __attribute__((ext_vector_type(8))) short short8;
typedef __attribute__((ext_vector_type(4))) short short4v;
typedef __attribute__((ext_vector_type(4))) float f32x4;

__device__ inline float bf2f(unsigned short b) {
    unsigned u = ((unsigned)b) << 16;
    return __builtin_bit_cast(float, u);
}
__device__ inline unsigned short f2bf(float f) {   // round-to-nearest-even
    unsigned u = __builtin_bit_cast(unsigned, f);
    unsigned r = u + 0x7fffu + ((u >> 16) & 1u);
    return (unsigned short)(r >> 16);
}
__device__ inline f32x4 mfma16(short8 a, short8 b, f32x4 c) {
    return __builtin_amdgcn_mfma_f32_16x16x32_bf16(a, b, c, 0, 0, 0);
}
// A-frag: lane holds A[m=lane&15][k=(lane>>4)*8+j]; B-frag: B[k][n=lane&15];
// C/D: col=lane&15, row=(lane>>4)*4+reg (learn_hip m89).

// ---------------------------------------------------------------------------
// VALU fp32 GEMM (proven R9): C = act(A@B + bias) (+=C if ACCUM). 64x64 tile, BK=16.
// ---------------------------------------------------------------------------
template <int AISBF, int ACT, int ACCUM>
__launch_bounds__(256)
__global__ void gemmV(const void* __restrict__ Av, const float* __restrict__ B,
                      const float* __restrict__ bias, float* __restrict__ C,
                      int M, int N, int K) {
    __shared__ float As[64][17];
    __shared__ float Bs[16][68];
    const int t = threadIdx.x;
    const int row0 = blockIdx.y * 64, col0 = blockIdx.x * 64;
    const int tx = t & 15, ty = t >> 4;

    float acc[4][4];
    #pragma unroll
    for (int i = 0; i < 4; i++)
        #pragma unroll
        for (int j = 0; j < 4; j++) acc[i][j] = 0.0f;

    for (int kt = 0; kt < K; kt += 16) {
        {
            const int row = t >> 2, kq = (t & 3) * 4;
            if (AISBF) {
                const unsigned short* a16 = (const unsigned short*)Av;
                #pragma unroll
                for (int e = 0; e < 4; e++)
                    As[row][kq + e] = bf2f(a16[(size_t)(row0 + row) * K + kt + kq + e]);
            } else {
                const float* a32 = (const float*)Av;
                f32x4 v = *(const f32x4*)&a32[(size_t)(row0 + row) * K + kt + kq];
                #pragma unroll
                for (int e = 0; e < 4; e++) As[row][kq + e] = v[e];
            }
        }
        {
            const int k = t >> 4, n4 = (t & 15) * 4;
            f32x4 v = *(const f32x4*)&B[(size_t)(kt + k) * N + col0 + n4];
            #pragma unroll
            for (int e = 0; e < 4; e++) Bs[k][n4 + e] = v[e];
        }
        __syncthreads();
        #pragma unroll
        for (int kk = 0; kk < 16; kk++) {
            float a0 = As[ty * 4 + 0][kk], a1 = As[ty * 4 + 1][kk];
            float a2 = As[ty * 4 + 2][kk], a3 = As[ty * 4 + 3][kk];
            float b0 = Bs[kk][tx * 4 + 0], b1 = Bs[kk][tx * 4 + 1];
            float b2 = Bs[kk][tx * 4 + 2], b3 = Bs[kk][tx * 4 + 3];
            acc[0][0] += a0 * b0; acc[0][1] += a0 * b1; acc[0][2] += a0 * b2; acc[0][3] += a0 * b3;
            acc[1][0] += a1 * b0; acc[1][1] += a1 * b1; acc[1][2] += a1 * b2; acc[1][3] += a1 * b3;
            acc[2][0] += a2 * b0; acc[2][1] += a2 * b1; acc[2][2] += a2 * b2; acc[2][3] += a2 * b3;
            acc[3][0] += a3 * b0; acc[3][1] += a3 * b1; acc[3][2] += a3 * b2; acc[3][3] += a3 * b3;
        }
        __syncthreads();
    }
    #pragma unroll
    for (int i = 0; i < 4; i++) {
        const int row = row0 + ty * 4 + i;
        #pragma unroll
        for (int j = 0; j < 4; j++) {
            const int col = col0 + tx * 4 + j;
            float v = acc[i][j] + bias[col];
            if (ACT == 1) v = v > 0.0f ? v : 0.01f * v;
            size_t idx = (size_t)row * N + col;
            if (ACCUM) v += C[idx];
            C[idx] = v;
        }
    }
}

// ---------------------------------------------------------------------------
__global__ void colsum_k(const float* __restrict__ x, float* __restrict__ out) {
    int d = threadIdx.x, b = blockIdx.x;
    float s = 0.0f;
    int i0 = b * 128;
    for (int i = 0; i < 128; i++) s += x[(size_t)(i0 + i) * 256 + d];
    out[b * 256 + d] = s;
}
__global__ void meanred_k(const float* __restrict__ p, float* __restrict__ mean) {
    int d = threadIdx.x;
    float s = 0.0f;
    for (int b = 0; b < 64; b++) s += p[b * 256 + d];
    mean[d] = s * (1.0f / 8192.0f);
}
__global__ void finalize_x(float* __restrict__ x, const float* __restrict__ mean) {
    size_t idx = (size_t)blockIdx.x * blockDim.x + threadIdx.x;
    f32x4 v = *(f32x4*)&x[idx * 4];
    int d4 = (int)((idx * 4) & 255);
    f32x4 m = *(const f32x4*)&mean[d4];
    #pragma unroll
    for (int e = 0; e < 4; e++) v[e] = (v[e] + m[e]) * 0.5f;
    *(f32x4*)&x[idx * 4] = v;
}
__global__ void f2bf_k(const float* __restrict__ src, unsigned short* __restrict__ dst, int n4) {
    size_t idx = (size_t)blockIdx.x * blockDim.x + threadIdx.x;
    if (idx >= (size_t)n4) return;
    f32x4 v = *(const f32x4*)&src[idx * 4];
    short4v h;
    #pragma unroll
    for (int e = 0; e < 4; e++) h[e] = (short)f2bf(v[e]);
    *(short4v*)&dst[idx * 4] = h;
}
__global__ void cpy_k(const float* __restrict__ src, float* __restrict__ dst) {
    size_t idx = (size_t)blockIdx.x * blockDim.x + threadIdx.x;
    *(f32x4*)&dst[idx * 4] = *(const f32x4*)&src[idx * 4];
}

// ---------------------------------------------------------------------------
// screen2 helpers: monotone fp32->uint key, packed (score | 11-bit col) top-8.
// ---------------------------------------------------------------------------
__device__ inline unsigned fkey(float f) {
    unsigned u = __builtin_bit_cast(unsigned, f);
    unsigned s = (unsigned)((int)u >> 31);          // 0 or 0xFFFFFFFF
    return u ^ (s | 0x80000000u);                   // order-preserving
}
__device__ inline float bucket_low(unsigned key) {  // lower edge of key's value bucket
    unsigned kh = key & 0xFFFFF800u;
    unsigned u = (kh & 0x80000000u) ? (kh ^ 0x80000000u) : ~kh;
    return __builtin_bit_cast(float, u);
}
template<int NK>
__device__ inline void insertK(unsigned (&tk)[NK], unsigned key) {
    #pragma unroll
    for (int k = 0; k < NK; k++) {
        unsigned nxt = (k < NK - 1) ? tk[k + 1] : 0xFFFFFFFFu;
        bool shift = (key > nxt);
        bool here  = !shift && (key > tk[k]);
        tk[k] = shift ? nxt : (here ? key : tk[k]);
    }
}
__device__ inline void gload_lds16(const unsigned short* g, unsigned short* l) {
    __builtin_amdgcn_global_load_lds(
        (const __attribute__((address_space(1))) void*)g,
        (__attribute__((address_space(3))) void*)l, 16, 0, 0);
}

// ---------------------------------------------------------------------------
// screen2 R11: logits = e_h @ e_t^T (bf16 MFMA), top-8 per column quarter per row.
// Grid (4 quarters, 128 row-blocks of 64); 256 thr = 4 waves x 16 rows.
// A-frags register-resident. B tile: 32 cols x K=256 bf16, stored as 16B granules
// XOR-swizzled (granule ^ (col&7)) so wave b128 reads spread 8 lanes/bank-quad
// (the minimum); staged via global_load_lds (linear LDS dest = chunk*1KB + lane*16B,
// inverse-swizzled global source), double-buffered -> 1 barrier/tile.
// Top-8 per (lane,row-slice) as packed uint keys (score hi-21 bits | colq lo-11);
// shadow float threshold = bucket_low(tk[0]) for the cheap pre-check;
// shfl_xor butterfly merge across the 16 col-slice lanes on keys only.
// ---------------------------------------------------------------------------
__launch_bounds__(256)
__global__ void screen2(const unsigned short* __restrict__ eh16,
                        const unsigned short* __restrict__ et16,
                        int* __restrict__ candi) {
    __shared__ __align__(16) unsigned short Bs[2][8192];   // 2 x (32 cols x 256 k)
    const int t = threadIdx.x;
    const int cs = blockIdx.x;
    const int r0 = blockIdx.y * 64;
    const int w = t >> 6, lid = t & 63, g = lid >> 4, m16 = lid & 15;
    const int ar = w * 16;

    short8 afr[8];   // this wave's 16 rows, K=256
    #pragma unroll
    for (int ks = 0; ks < 8; ks++)
        afr[ks] = *(const short8*)&eh16[(size_t)(r0 + ar + m16) * 256 + ks * 32 + g * 8];

    unsigned tk[4][8];
    float thr[4];
    #pragma unroll
    for (int r = 0; r < 4; r++) {
        thr[r] = -3.0e38f;
        #pragma unroll
        for (int q = 0; q < 8; q++) tk[r][q] = 0u;
    }

    // staging map: chunk = w*4+c; linear LDS granule L = chunk*64 + lid;
    // L holds (col = L>>5, gorig = (gs&24)|((gs^col)&7)) where gs = L&31.
    int scol[4], goff[4], ldsl[4];
    #pragma unroll
    for (int c = 0; c < 4; c++) {
        int L = (w * 4 + c) * 64 + lid;
        int col = L >> 5, gs = L & 31;
        int gorig = (gs & 24) | ((gs ^ col) & 7);
        scol[c] = col; goff[c] = gorig * 8; ldsl[c] = L * 8;
    }

    // prologue: stage tile 0 into buf 0
    #pragma unroll
    for (int c = 0; c < 4; c++)
        gload_lds16(&et16[(size_t)(cs * 2048 + scol[c]) * 256 + goff[c]], &Bs[0][ldsl[c]]);
    __syncthreads();

    const int swz = m16 & 7;
    for (int tile = 0; tile < 64; tile++) {
        const int cur = tile & 1;
        if (tile + 1 < 64) {   // prefetch next tile into the other buffer
            const int j1 = cs * 2048 + (tile + 1) * 32;
            #pragma unroll
            for (int c = 0; c < 4; c++)
                gload_lds16(&et16[(size_t)(j1 + scol[c]) * 256 + goff[c]],
                            &Bs[cur ^ 1][ldsl[c]]);
        }
        f32x4 a0 = {0.0f, 0.0f, 0.0f, 0.0f}, a1 = a0;
        #pragma unroll
        for (int ks = 0; ks < 8; ks++) {
            const int gq = ks * 4 + g;
            short8 b0 = *(const short8*)&Bs[cur][(m16 * 32 + (gq ^ swz)) * 8];
            short8 b1 = *(const short8*)&Bs[cur][((16 + m16) * 32 + (gq ^ swz)) * 8];
            a0 = mfma16(afr[ks], b0, a0);
            a1 = mfma16(afr[ks], b1, a1);
        }
        const unsigned cq0 = (unsigned)(tile * 32 + m16), cq1 = cq0 + 16u;
        #pragma unroll
        for (int r = 0; r < 4; r++) {
            float v0 = a0[r];
            if (v0 >= thr[r]) {
                unsigned key = (fkey(v0) & 0xFFFFF800u) | cq0;
                if (key > tk[r][0]) {
                    insertK<8>(tk[r], key);
                    thr[r] = (tk[r][0] == 0u) ? -3.0e38f : bucket_low(tk[r][0]);
                }
            }
            float v1 = a1[r];
            if (v1 >= thr[r]) {
                unsigned key = (fkey(v1) & 0xFFFFF800u) | cq1;
                if (key > tk[r][0]) {
                    insertK<8>(tk[r], key);
                    thr[r] = (tk[r][0] == 0u) ? -3.0e38f : bucket_low(tk[r][0]);
                }
            }
        }
        __syncthreads();   // next-tile loads landed; reads of Bs[cur] done
    }

    // butterfly merge across the 16 lanes (same g group) sharing each row
    #pragma unroll
    for (int step = 1; step < 16; step <<= 1) {
        #pragma unroll
        for (int r = 0; r < 4; r++) {
            unsigned ok[8];
            #pragma unroll
            for (int q = 0; q < 8; q++)
                ok[q] = (unsigned)__shfl_xor((int)tk[r][q], step);
            #pragma unroll
            for (int q = 0; q < 8; q++)
                if (ok[q] > tk[r][0]) insertK<8>(tk[r], ok[q]);
        }
    }
    if (m16 == 0) {
        #pragma unroll
        for (int r = 0; r < 4; r++) {
            const int row = r0 + ar + g * 4 + r;
            #pragma unroll
            for (int q = 0; q < 8; q++)
                candi[(size_t)row * 32 + cs * 8 + q] = cs * 2048 + (int)(tk[r][q] & 0x7FFu);
        }
    }
}

// ---------------------------------------------------------------------------
// Stage D (proven R9): fp64 rescore of 32 candidates, top-6, softmax p, message,
// ka softmax, e_Nh -> m1/m2 bf16. One wave per row.
// ---------------------------------------------------------------------------
__launch_bounds__(64)
__global__ void stageD(const float* __restrict__ eh, const float* __restrict__ et,
                       const int* __restrict__ candi,
                       unsigned short* __restrict__ m1, unsigned short* __restrict__ m2) {
    const int i = blockIdx.x, l = threadIdx.x;
    __shared__ int sj[32];
    __shared__ double slog[32];
    __shared__ float sred[64 * 12];
    __shared__ float ssum[12];
    __shared__ int selj[6];
    __shared__ float sp[6], skp[6];

    if (l < 32) sj[l] = candi[(size_t)i * 32 + l] & 8191;
    __syncthreads();
    f32x4 eh4 = *(const f32x4*)&eh[(size_t)i * 256 + l * 4];

    for (int c = 0; c < 32; c++) {
        const f32x4 t4 = *(const f32x4*)&et[(size_t)sj[c] * 256 + l * 4];
        double p = (double)eh4[0] * t4[0] + (double)eh4[1] * t4[1] +
                   (double)eh4[2] * t4[2] + (double)eh4[3] * t4[3];
        #pragma unroll
        for (int off = 1; off < 64; off <<= 1) p += __shfl_xor(p, off);
        if (l == 0) slog[c] = p * 0.0625;
    }
    __syncthreads();
    if (l == 0) {
        unsigned used = 0;
        float w6[6];
        for (int s = 0; s < 6; s++) {
            double best = -1.0e300; int bj = 0x7fffffff, bc = 0;
            for (int c = 0; c < 32; c++) {
                if ((used >> c) & 1u) continue;
                double v = slog[c]; int j = sj[c];
                if (v > best || (v == best && j < bj)) { best = v; bj = j; bc = c; }
            }
            used |= 1u << bc;
            selj[s] = bj; w6[s] = (float)best;
        }
        float mx = w6[0];
        for (int s = 1; s < 6; s++) mx = fmaxf(mx, w6[s]);
        float se = 0.0f, e6[6];
        for (int s = 0; s < 6; s++) { e6[s] = expf(w6[s] - mx); se += e6[s]; }
        for (int s = 0; s < 6; s++) sp[s] = e6[s] / se;
    }
    __syncthreads();
    f32x4 nb[6];
    #pragma unroll
    for (int k = 0; k < 6; k++) nb[k] = *(const f32x4*)&et[(size_t)(selj[k] & 8191) * 256 + l * 4];
    #pragma unroll
    for (int k = 0; k < 6; k++) {
        float pk = sp[k];
        float pn = nb[k][0] + nb[k][1] + nb[k][2] + nb[k][3];
        float pg = 0.0f;
        #pragma unroll
        for (int e = 0; e < 4; e++) {
            float ehd = eh4[e], nbd = nb[k][e];
            float ehr = pk * nbd + (1.0f - pk) * ehd;
            pg += tanhf(ehd + ehr);
        }
        sred[l * 12 + k] = pn;
        sred[l * 12 + 6 + k] = pg;
    }
    __syncthreads();
    if (l < 12) {
        float s = 0.0f;
        for (int ll = 0; ll < 64; ll++) s += sred[ll * 12 + l];
        ssum[l] = s;
    }
    __syncthreads();
    if (l == 0) {
        float ka[6], mx = -3.0e38f, se = 0.0f;
        for (int k = 0; k < 6; k++) { ka[k] = ssum[k] * ssum[6 + k]; mx = fmaxf(mx, ka[k]); }
        for (int k = 0; k < 6; k++) { ka[k] = expf(ka[k] - mx); se += ka[k]; }
        for (int k = 0; k < 6; k++) skp[k] = ka[k] / se;
    }
    __syncthreads();
    f32x4 enh = {0.0f, 0.0f, 0.0f, 0.0f};
    #pragma unroll
    for (int k = 0; k < 6; k++) {
        float kp = skp[k];
        #pragma unroll
        for (int e = 0; e < 4; e++) enh[e] += kp * nb[k][e];
    }
    short4v h1, h2;
    #pragma unroll
    for (int e = 0; e < 4; e++) {
        h1[e] = (short)f2bf(eh4[e] + enh[e]);
        h2[e] = (short)f2bf(eh4[e] * enh[e]);
    }
    *(short4v*)&m1[(size_t)i * 256 + l * 4] = h1;
    *(short4v*)&m2[(size_t)i * 256 + l * 4] = h2;
}

// ---------------------------------------------------------------------------
// Readout: g1 = leaky(emsg@Ag1+bg1) via gemmV; then glog = g1@Ag2 + bg2.
// ---------------------------------------------------------------------------
__launch_bounds__(256)
__global__ void gate2_k(const float* __restrict__ g1, const float* __restrict__ Ag2,
                        const float* __restrict__ bg2, float* __restrict__ glog) {
    const int i = blockIdx.x * 256 + threadIdx.x;
    float s = 0.0f;
    #pragma unroll 4
    for (int h = 0; h < 128; h++) s += g1[(size_t)i * 128 + h] * Ag2[h];
    glog[i] = s + bg2[0];
}

__launch_bounds__(1024)
__global__ void softmax_g(const float* __restrict__ glog, float* __restrict__ gexp,
                          float* __restrict__ scal) {
    const int t = threadIdx.x;
    __shared__ float red[1024];
    float v[8];
    float m = -3.0e38f;
    #pragma unroll
    for (int c = 0; c < 8; c++) { v[c] = glog[t + c * 1024]; m = fmaxf(m, v[c]); }
    red[t] = m; __syncthreads();
    for (int st = 512; st > 0; st >>= 1) {
        if (t < st) red[t] = fmaxf(red[t], red[t + st]);
        __syncthreads();
    }
    float gm = red[0]; __syncthreads();
    float s = 0.0f;
    #pragma unroll
    for (int c = 0; c < 8; c++) {
        float e = expf(v[c] - gm);
        gexp[t + c * 1024] = e;
        s += e;
    }
    red[t] = s; __syncthreads();
    for (int st = 512; st > 0; st >>= 1) {
        if (t < st) red[t] += red[t + st];
        __syncthreads();
    }
    if (t == 0) scal[0] = 1.0f / red[0];
}

__launch_bounds__(256)
__global__ void wsum_k(const float* __restrict__ emsg, const float* __restrict__ gexp,
                       float* __restrict__ egp) {
    const int b = blockIdx.x, d = threadIdx.x;
    float s = 0.0f;
    const int i0 = b * 128;
    for (int i = 0; i < 128; i++) s += gexp[i0 + i] * emsg[(size_t)(i0 + i) * 256 + d];
    egp[b * 256 + d] = s;
}
__global__ void egfinal_f(const float* __restrict__ egp, const float* __restrict__ scal,
                          float* __restrict__ out) {
    const int d = threadIdx.x;
    float s = 0.0f;
    for (int b = 0; b < 64; b++) s += egp[b * 256 + d];
    out[d] = s * scal[0];
}

__global__ void wsbad_k(float* __restrict__ out) { out[3] = 9000.0f; }

// ---------------------------------------------------------------------------
extern "C" void kernel_launch(void* const* d_in, const int* in_sizes, int n_in,
                              void* d_out, int out_size, void* d_ws, size_t ws_size,
                              hipStream_t stream) {
    (void)in_sizes; (void)n_in; (void)out_size;
    const float* x_path = (const float*)d_in[0];
    const float* fc1_W  = (const float*)d_in[1];
    const float* fc1_b  = (const float*)d_in[2];
    const float* Wh     = (const float*)d_in[3];
    const float* bh     = (const float*)d_in[4];
    const float* Wt     = (const float*)d_in[5];
    const float* bt     = (const float*)d_in[6];
    const float* W1     = (const float*)d_in[7];
    const float* b1     = (const float*)d_in[8];
    const float* W2     = (const float*)d_in[9];
    const float* b2     = (const float*)d_in[10];
    const float* Ag1    = (const float*)d_in[11];
    const float* bg1    = (const float*)d_in[12];
    const float* Ag2    = (const float*)d_in[13];
    const float* bg2    = (const float*)d_in[14];
    float* out_f = (float*)d_out;   // fp32: e_msg [0,2097152), e_g [2097152,2097408)

    const size_t WS_NEEDED = 26412048;
    if (ws_size < WS_NEEDED) {
        hipLaunchKernelGGL(wsbad_k, dim3(1), dim3(1), 0, stream, out_f);
        return;
    }

    char* ws = (char*)d_ws;
    float* x     = (float*)(ws + 0);
    unsigned short* eh16 = (unsigned short*)(ws + 0);
    unsigned short* et16 = (unsigned short*)(ws + 4194304);
    unsigned short* m1b  = (unsigned short*)(ws + 0);
    unsigned short* m2b  = (unsigned short*)(ws + 4194304);
    float* g1    = (float*)(ws + 0);          // 8192x128 fp32 (after m1b/m2b dead)
    float* eh    = (float*)(ws + 8388608);
    float* emsg  = (float*)(ws + 8388608);
    float* et    = (float*)(ws + 16777216);
    int*   candi = (int*)  (ws + 25165824);
    float* meanp = (float*)(ws + 26214400);
    float* meanv = (float*)(ws + 26279936);
    float* glog  = (float*)(ws + 26280960);
    float* gexp  = (float*)(ws + 26313728);
    float* egp   = (float*)(ws + 26346496);
    float* scal  = (float*)(ws + 26412032);

    dim3 gg(4, 128);
    // 1) x = leaky(x_path @ fc1_W + fc1_b)
    hipLaunchKernelGGL((gemmV<0, 1, 0>), gg, dim3(256), 0, stream,
                       (const void*)x_path, fc1_W, fc1_b, x, 8192, 256, 1024);
    // 2) x = (x + mean(x)) * 0.5
    hipLaunchKernelGGL(colsum_k, dim3(64), dim3(256), 0, stream, x, meanp);
    hipLaunchKernelGGL(meanred_k, dim3(1), dim3(256), 0, stream, meanp, meanv);
    hipLaunchKernelGGL(finalize_x, dim3(2048), dim3(256), 0, stream, x, meanv);
    // 3) e_h, e_t (fp32 exact)
    hipLaunchKernelGGL((gemmV<0, 0, 0>), gg, dim3(256), 0, stream,
                       (const void*)x, Wh, bh, eh, 8192, 256, 256);
    hipLaunchKernelGGL((gemmV<0, 0, 0>), gg, dim3(256), 0, stream,
                       (const void*)x, Wt, bt, et, 8192, 256, 256);
    // 4) bf16 copies for screening
    hipLaunchKernelGGL(f2bf_k, dim3(2048), dim3(256), 0, stream, eh, eh16, 524288);
    hipLaunchKernelGGL(f2bf_k, dim3(2048), dim3(256), 0, stream, et, et16, 524288);
    // 5) screening: register top-8 per quarter -> 32 candidates/row
    hipLaunchKernelGGL(screen2, dim3(4, 128), dim3(256), 0, stream, eh16, et16, candi);
    // 6) fp64 select + message -> m1b/m2b
    hipLaunchKernelGGL(stageD, dim3(8192), dim3(64), 0, stream, eh, et, candi, m1b, m2b);
    // 7) e_msg = leaky(m1@W1+b1) + leaky(m2@W2+b2)
    hipLaunchKernelGGL((gemmV<1, 1, 0>), gg, dim3(256), 0, stream,
                       (const void*)m1b, W1, b1, emsg, 8192, 256, 256);
    hipLaunchKernelGGL((gemmV<1, 1, 1>), gg, dim3(256), 0, stream,
                       (const void*)m2b, W2, b2, emsg, 8192, 256, 256);
    // 8) output 0: e_msg fp32
    hipLaunchKernelGGL(cpy_k, dim3(2048), dim3(256), 0, stream, emsg, out_f);
    // 9) readout: g1 = leaky(emsg@Ag1+bg1); glog = g1@Ag2+bg2; softmax; weighted sum
    hipLaunchKernelGGL((gemmV<0, 1, 0>), dim3(2, 128), dim3(256), 0, stream,
                       (const void*)emsg, Ag1, bg1, g1, 8192, 128, 256);
    hipLaunchKernelGGL(gate2_k, dim3(32), dim3(256), 0, stream, g1, Ag2, bg2, glog);
    hipLaunchKernelGGL(softmax_g, dim3(1), dim3(1024), 0, stream, glog, gexp, scal);
    hipLaunchKernelGGL(wsum_k, dim3(64), dim3(256), 0, stream, emsg, gexp, egp);
    hipLaunchKernelGGL(egfinal_f, dim3(1), dim3(256), 0, stream, egp, scal, out_f + 2097152);
}

// Round 2
// 462.544 us; speedup vs baseline: 1.1880x; 1.1062x over previous
//
#include <hip/hip_runtime.h>

// MOTCAT_Surv R12. R11 passed (absmax 0.0156, 511 us); screen2 still the whale
// (129 us, VALUBusy 59%, MfmaUtil 10.5%) -- divergent insertK executes at ~every
// check site (512/wave x ~35 VALU). This round: (a) swap MFMA operands
// (mfma(et_lds, eh_regs)) so each lane's 8 scores/tile are ONE eh row across 8 et
// cols -> single top-6 queue/lane (was 4x top-8), merge over 4 lanes (2 shfl steps);
// (b) branchless med3-style insert (tk[k]=max(min(key,tk[k+1]),tk[k]), 2 VALU/slot)
// run unconditionally -> no divergence, no thresholds. Per-lane/LDS data movement is
// byte-identical to R11 (A/B frag per-lane layouts coincide under the swap).
// Top-6/lane + 6 in-lane eviction witnesses keeps the quarter top-6 guarantee;
// output = 2-step butterfly merged top-8 (sentinel-padded), distinct cols.
// Everything else identical to R11.

typedef __attribute__((ext_vector_type(8))) short short8;
typedef __attribute__((ext_vector_type(4))) short short4v;
typedef __attribute__((ext_vector_type(4))) float f32x4;

__device__ inline float bf2f(unsigned short b) {
    unsigned u = ((unsigned)b) << 16;
    return __builtin_bit_cast(float, u);
}
__device__ inline unsigned short f2bf(float f) {   // round-to-nearest-even
    unsigned u = __builtin_bit_cast(unsigned, f);
    unsigned r = u + 0x7fffu + ((u >> 16) & 1u);
    return (unsigned short)(r >> 16);
}
__device__ inline f32x4 mfma16(short8 a, short8 b, f32x4 c) {
    return __builtin_amdgcn_mfma_f32_16x16x32_bf16(a, b, c, 0, 0, 0);
}
// A-frag: lane holds A[m=lane&15][k=(lane>>4)*8+j]; B-frag: B[k][n=lane&15];
// C/D: col=lane&15 (n), row=(lane>>4)*4+reg (m) (learn_hip m89).

// ---------------------------------------------------------------------------
// VALU fp32 GEMM (proven R9): C = act(A@B + bias) (+=C if ACCUM). 64x64 tile, BK=16.
// ---------------------------------------------------------------------------
template <int AISBF, int ACT, int ACCUM>
__launch_bounds__(256)
__global__ void gemmV(const void* __restrict__ Av, const float* __restrict__ B,
                      const float* __restrict__ bias, float* __restrict__ C,
                      int M, int N, int K) {
    __shared__ float As[64][17];
    __shared__ float Bs[16][68];
    const int t = threadIdx.x;
    const int row0 = blockIdx.y * 64, col0 = blockIdx.x * 64;
    const int tx = t & 15, ty = t >> 4;

    float acc[4][4];
    #pragma unroll
    for (int i = 0; i < 4; i++)
        #pragma unroll
        for (int j = 0; j < 4; j++) acc[i][j] = 0.0f;

    for (int kt = 0; kt < K; kt += 16) {
        {
            const int row = t >> 2, kq = (t & 3) * 4;
            if (AISBF) {
                const unsigned short* a16 = (const unsigned short*)Av;
                #pragma unroll
                for (int e = 0; e < 4; e++)
                    As[row][kq + e] = bf2f(a16[(size_t)(row0 + row) * K + kt + kq + e]);
            } else {
                const float* a32 = (const float*)Av;
                f32x4 v = *(const f32x4*)&a32[(size_t)(row0 + row) * K + kt + kq];
                #pragma unroll
                for (int e = 0; e < 4; e++) As[row][kq + e] = v[e];
            }
        }
        {
            const int k = t >> 4, n4 = (t & 15) * 4;
            f32x4 v = *(const f32x4*)&B[(size_t)(kt + k) * N + col0 + n4];
            #pragma unroll
            for (int e = 0; e < 4; e++) Bs[k][n4 + e] = v[e];
        }
        __syncthreads();
        #pragma unroll
        for (int kk = 0; kk < 16; kk++) {
            float a0 = As[ty * 4 + 0][kk], a1 = As[ty * 4 + 1][kk];
            float a2 = As[ty * 4 + 2][kk], a3 = As[ty * 4 + 3][kk];
            float b0 = Bs[kk][tx * 4 + 0], b1 = Bs[kk][tx * 4 + 1];
            float b2 = Bs[kk][tx * 4 + 2], b3 = Bs[kk][tx * 4 + 3];
            acc[0][0] += a0 * b0; acc[0][1] += a0 * b1; acc[0][2] += a0 * b2; acc[0][3] += a0 * b3;
            acc[1][0] += a1 * b0; acc[1][1] += a1 * b1; acc[1][2] += a1 * b2; acc[1][3] += a1 * b3;
            acc[2][0] += a2 * b0; acc[2][1] += a2 * b1; acc[2][2] += a2 * b2; acc[2][3] += a2 * b3;
            acc[3][0] += a3 * b0; acc[3][1] += a3 * b1; acc[3][2] += a3 * b2; acc[3][3] += a3 * b3;
        }
        __syncthreads();
    }
    #pragma unroll
    for (int i = 0; i < 4; i++) {
        const int row = row0 + ty * 4 + i;
        #pragma unroll
        for (int j = 0; j < 4; j++) {
            const int col = col0 + tx * 4 + j;
            float v = acc[i][j] + bias[col];
            if (ACT == 1) v = v > 0.0f ? v : 0.01f * v;
            size_t idx = (size_t)row * N + col;
            if (ACCUM) v += C[idx];
            C[idx] = v;
        }
    }
}

// ---------------------------------------------------------------------------
__global__ void colsum_k(const float* __restrict__ x, float* __restrict__ out) {
    int d = threadIdx.x, b = blockIdx.x;
    float s = 0.0f;
    int i0 = b * 128;
    for (int i = 0; i < 128; i++) s += x[(size_t)(i0 + i) * 256 + d];
    out[b * 256 + d] = s;
}
__global__ void meanred_k(const float* __restrict__ p, float* __restrict__ mean) {
    int d = threadIdx.x;
    float s = 0.0f;
    for (int b = 0; b < 64; b++) s += p[b * 256 + d];
    mean[d] = s * (1.0f / 8192.0f);
}
__global__ void finalize_x(float* __restrict__ x, const float* __restrict__ mean) {
    size_t idx = (size_t)blockIdx.x * blockDim.x + threadIdx.x;
    f32x4 v = *(f32x4*)&x[idx * 4];
    int d4 = (int)((idx * 4) & 255);
    f32x4 m = *(const f32x4*)&mean[d4];
    #pragma unroll
    for (int e = 0; e < 4; e++) v[e] = (v[e] + m[e]) * 0.5f;
    *(f32x4*)&x[idx * 4] = v;
}
__global__ void f2bf_k(const float* __restrict__ src, unsigned short* __restrict__ dst, int n4) {
    size_t idx = (size_t)blockIdx.x * blockDim.x + threadIdx.x;
    if (idx >= (size_t)n4) return;
    f32x4 v = *(const f32x4*)&src[idx * 4];
    short4v h;
    #pragma unroll
    for (int e = 0; e < 4; e++) h[e] = (short)f2bf(v[e]);
    *(short4v*)&dst[idx * 4] = h;
}
__global__ void cpy_k(const float* __restrict__ src, float* __restrict__ dst) {
    size_t idx = (size_t)blockIdx.x * blockDim.x + threadIdx.x;
    *(f32x4*)&dst[idx * 4] = *(const f32x4*)&src[idx * 4];
}

// ---------------------------------------------------------------------------
// screen2 helpers: monotone fp32->uint key; branchless sorted-insert (ascending,
// tk[0]=min). med3 identity: tk[k] = max(min(key, tk[k+1]), tk[k]) -- 2 VALU/slot,
// reads-before-writes are safe in ascending order (iter k reads old tk[k+1]).
// ---------------------------------------------------------------------------
__device__ inline unsigned fkey(float f) {
    unsigned u = __builtin_bit_cast(unsigned, f);
    unsigned s = (unsigned)((int)u >> 31);          // 0 or 0xFFFFFFFF
    return u ^ (s | 0x80000000u);                   // order-preserving
}
template<int NK>
__device__ inline void ins(unsigned (&tk)[NK], unsigned key) {
    #pragma unroll
    for (int k = 0; k < NK - 1; k++) {
        unsigned lo = key < tk[k + 1] ? key : tk[k + 1];
        tk[k] = lo > tk[k] ? lo : tk[k];
    }
    tk[NK - 1] = key > tk[NK - 1] ? key : tk[NK - 1];
}
__device__ inline void gload_lds16(const unsigned short* g, unsigned short* l) {
    __builtin_amdgcn_global_load_lds(
        (const __attribute__((address_space(1))) void*)g,
        (__attribute__((address_space(3))) void*)l, 16, 0, 0);
}

// ---------------------------------------------------------------------------
// screen2 R12: logits = e_h @ e_t^T, swapped MFMA (A = et tile from LDS, B = eh
// rows from regs) => lane (g,m16) scores eh row (r0+w*16+m16), et cols
// tile*32 + {g*4+r, 16+g*4+r}. Single branchless top-6 queue per lane (packed
// keys: score hi-21 bits | colq lo-11), merged at the end across the 4 g-lanes
// per row via 2-step shfl_xor butterfly into top-8 -> candi (8 distinct cols per
// quarter, superset of the quarter's true top-6; stageD rescores in fp64).
// B tile staging identical to R11: XOR-swizzled 16B granules via global_load_lds
// (linear LDS dest, inverse-swizzled global source), double-buffered.
// ---------------------------------------------------------------------------
__launch_bounds__(256)
__global__ void screen2(const unsigned short* __restrict__ eh16,
                        const unsigned short* __restrict__ et16,
                        int* __restrict__ candi) {
    __shared__ __align__(16) unsigned short Bs[2][8192];   // 2 x (32 cols x 256 k)
    const int t = threadIdx.x;
    const int cs = blockIdx.x;
    const int r0 = blockIdx.y * 64;
    const int w = t >> 6, lid = t & 63, g = lid >> 4, m16 = lid & 15;
    const int ar = w * 16;

    short8 bfr[8];   // eh B-frags: lane's row = r0+ar+m16, k = ks*32 + g*8 + j
    #pragma unroll
    for (int ks = 0; ks < 8; ks++)
        bfr[ks] = *(const short8*)&eh16[(size_t)(r0 + ar + m16) * 256 + ks * 32 + g * 8];

    unsigned tk[6];
    #pragma unroll
    for (int q = 0; q < 6; q++) tk[q] = 0u;

    // staging map: chunk = w*4+c; linear LDS granule L = chunk*64 + lid;
    // L holds (col = L>>5, gorig = (gs&24)|((gs^col)&7)) where gs = L&31.
    int scol[4], goff[4], ldsl[4];
    #pragma unroll
    for (int c = 0; c < 4; c++) {
        int L = (w * 4 + c) * 64 + lid;
        int col = L >> 5, gs = L & 31;
        int gorig = (gs & 24) | ((gs ^ col) & 7);
        scol[c] = col; goff[c] = gorig * 8; ldsl[c] = L * 8;
    }

    // prologue: stage tile 0 into buf 0
    #pragma unroll
    for (int c = 0; c < 4; c++)
        gload_lds16(&et16[(size_t)(cs * 2048 + scol[c]) * 256 + goff[c]], &Bs[0][ldsl[c]]);
    __syncthreads();

    const int swz = m16 & 7;
    for (int tile = 0; tile < 64; tile++) {
        const int cur = tile & 1;
        if (tile + 1 < 64) {   // prefetch next tile into the other buffer
            const int j1 = cs * 2048 + (tile + 1) * 32;
            #pragma unroll
            for (int c = 0; c < 4; c++)
                gload_lds16(&et16[(size_t)(j1 + scol[c]) * 256 + goff[c]],
                            &Bs[cur ^ 1][ldsl[c]]);
        }
        f32x4 a0 = {0.0f, 0.0f, 0.0f, 0.0f}, a1 = a0;
        #pragma unroll
        for (int ks = 0; ks < 8; ks++) {
            const int gq = ks * 4 + g;
            short8 e0 = *(const short8*)&Bs[cur][(m16 * 32 + (gq ^ swz)) * 8];
            short8 e1 = *(const short8*)&Bs[cur][((16 + m16) * 32 + (gq ^ swz)) * 8];
            a0 = mfma16(e0, bfr[ks], a0);   // swapped: A = et (LDS), B = eh (regs)
            a1 = mfma16(e1, bfr[ks], a1);
        }
        // lane's scores: row = r0+ar+m16; cols = tile*32 + g*4 + r (a0), +16 (a1)
        const unsigned cb = (unsigned)(tile * 32 + g * 4);
        #pragma unroll
        for (int r = 0; r < 4; r++) {
            ins<6>(tk, (fkey(a0[r]) & 0xFFFFF800u) | (cb + (unsigned)r));
            ins<6>(tk, (fkey(a1[r]) & 0xFFFFF800u) | (cb + 16u + (unsigned)r));
        }
        __syncthreads();   // next-tile loads landed; reads of Bs[cur] done
    }

    // widen to 8 (sentinels) and butterfly-merge across the 4 g-lanes of this row
    unsigned tk8[8];
    tk8[0] = 0u; tk8[1] = 0u;
    #pragma unroll
    for (int q = 0; q < 6; q++) tk8[q + 2] = tk[q];
    #pragma unroll
    for (int step = 16; step <= 32; step <<= 1) {
        unsigned ok[8];
        #pragma unroll
        for (int q = 0; q < 8; q++) ok[q] = (unsigned)__shfl_xor((int)tk8[q], step);
        #pragma unroll
        for (int q = 0; q < 8; q++) ins<8>(tk8, ok[q]);
    }
    if (g == 0) {
        const int row = r0 + ar + m16;
        #pragma unroll
        for (int q = 0; q < 8; q++)
            candi[(size_t)row * 32 + cs * 8 + q] = cs * 2048 + (int)(tk8[q] & 0x7FFu);
    }
}

// ---------------------------------------------------------------------------
// Stage D (proven R9): fp64 rescore of 32 candidates, top-6, softmax p, message,
// ka softmax, e_Nh -> m1/m2 bf16. One wave per row.
// ---------------------------------------------------------------------------
__launch_bounds__(64)
__global__ void stageD(const float* __restrict__ eh, const float* __restrict__ et,
                       const int* __restrict__ candi,
                       unsigned short* __restrict__ m1, unsigned short* __restrict__ m2) {
    const int i = blockIdx.x, l = threadIdx.x;
    __shared__ int sj[32];
    __shared__ double slog[32];
    __shared__ float sred[64 * 12];
    __shared__ float ssum[12];
    __shared__ int selj[6];
    __shared__ float sp[6], skp[6];

    if (l < 32) sj[l] = candi[(size_t)i * 32 + l] & 8191;
    __syncthreads();
    f32x4 eh4 = *(const f32x4*)&eh[(size_t)i * 256 + l * 4];

    for (int c = 0; c < 32; c++) {
        const f32x4 t4 = *(const f32x4*)&et[(size_t)sj[c] * 256 + l * 4];
        double p = (double)eh4[0] * t4[0] + (double)eh4[1] * t4[1] +
                   (double)eh4[2] * t4[2] + (double)eh4[3] * t4[3];
        #pragma unroll
        for (int off = 1; off < 64; off <<= 1) p += __shfl_xor(p, off);
        if (l == 0) slog[c] = p * 0.0625;
    }
    __syncthreads();
    if (l == 0) {
        unsigned used = 0;
        float w6[6];
        for (int s = 0; s < 6; s++) {
            double best = -1.0e300; int bj = 0x7fffffff, bc = 0;
            for (int c = 0; c < 32; c++) {
                if ((used >> c) & 1u) continue;
                double v = slog[c]; int j = sj[c];
                if (v > best || (v == best && j < bj)) { best = v; bj = j; bc = c; }
            }
            used |= 1u << bc;
            selj[s] = bj; w6[s] = (float)best;
        }
        float mx = w6[0];
        for (int s = 1; s < 6; s++) mx = fmaxf(mx, w6[s]);
        float se = 0.0f, e6[6];
        for (int s = 0; s < 6; s++) { e6[s] = expf(w6[s] - mx); se += e6[s]; }
        for (int s = 0; s < 6; s++) sp[s] = e6[s] / se;
    }
    __syncthreads();
    f32x4 nb[6];
    #pragma unroll
    for (int k = 0; k < 6; k++) nb[k] = *(const f32x4*)&et[(size_t)(selj[k] & 8191) * 256 + l * 4];
    #pragma unroll
    for (int k = 0; k < 6; k++) {
        float pk = sp[k];
        float pn = nb[k][0] + nb[k][1] + nb[k][2] + nb[k][3];
        float pg = 0.0f;
        #pragma unroll
        for (int e = 0; e < 4; e++) {
            float ehd = eh4[e], nbd = nb[k][e];
            float ehr = pk * nbd + (1.0f - pk) * ehd;
            pg += tanhf(ehd + ehr);
        }
        sred[l * 12 + k] = pn;
        sred[l * 12 + 6 + k] = pg;
    }
    __syncthreads();
    if (l < 12) {
        float s = 0.0f;
        for (int ll = 0; ll < 64; ll++) s += sred[ll * 12 + l];
        ssum[l] = s;
    }
    __syncthreads();
    if (l == 0) {
        float ka[6], mx = -3.0e38f, se = 0.0f;
        for (int k = 0; k < 6; k++) { ka[k] = ssum[k] * ssum[6 + k]; mx = fmaxf(mx, ka[k]); }
        for (int k = 0; k < 6; k++) { ka[k] = expf(ka[k] - mx); se += ka[k]; }
        for (int k = 0; k < 6; k++) skp[k] = ka[k] / se;
    }
    __syncthreads();
    f32x4 enh = {0.0f, 0.0f, 0.0f, 0.0f};
    #pragma unroll
    for (int k = 0; k < 6; k++) {
        float kp = skp[k];
        #pragma unroll
        for (int e = 0; e < 4; e++) enh[e] += kp * nb[k][e];
    }
    short4v h1, h2;
    #pragma unroll
    for (int e = 0; e < 4; e++) {
        h1[e] = (short)f2bf(eh4[e] + enh[e]);
        h2[e] = (short)f2bf(eh4[e] * enh[e]);
    }
    *(short4v*)&m1[(size_t)i * 256 + l * 4] = h1;
    *(short4v*)&m2[(size_t)i * 256 + l * 4] = h2;
}

// ---------------------------------------------------------------------------
// Readout: g1 = leaky(emsg@Ag1+bg1) via gemmV; then glog = g1@Ag2 + bg2.
// ---------------------------------------------------------------------------
__launch_bounds__(256)
__global__ void gate2_k(const float* __restrict__ g1, const float* __restrict__ Ag2,
                        const float* __restrict__ bg2, float* __restrict__ glog) {
    const int i = blockIdx.x * 256 + threadIdx.x;
    float s = 0.0f;
    #pragma unroll 4
    for (int h = 0; h < 128; h++) s += g1[(size_t)i * 128 + h] * Ag2[h];
    glog[i] = s + bg2[0];
}

__launch_bounds__(1024)
__global__ void softmax_g(const float* __restrict__ glog, float* __restrict__ gexp,
                          float* __restrict__ scal) {
    const int t = threadIdx.x;
    __shared__ float red[1024];
    float v[8];
    float m = -3.0e38f;
    #pragma unroll
    for (int c = 0; c < 8; c++) { v[c] = glog[t + c * 1024]; m = fmaxf(m, v[c]); }
    red[t] = m; __syncthreads();
    for (int st = 512; st > 0; st >>= 1) {
        if (t < st) red[t] = fmaxf(red[t], red[t + st]);
        __syncthreads();
    }
    float gm = red[0]; __syncthreads();
    float s = 0.0f;
    #pragma unroll
    for (int c = 0; c < 8; c++) {
        float e = expf(v[c] - gm);
        gexp[t + c * 1024] = e;
        s += e;
    }
    red[t] = s; __syncthreads();
    for (int st = 512; st > 0; st >>= 1) {
        if (t < st) red[t] += red[t + st];
        __syncthreads();
    }
    if (t == 0) scal[0] = 1.0f / red[0];
}

__launch_bounds__(256)
__global__ void wsum_k(const float* __restrict__ emsg, const float* __restrict__ gexp,
                       float* __restrict__ egp) {
    const int b = blockIdx.x, d = threadIdx.x;
    float s = 0.0f;
    const int i0 = b * 128;
    for (int i = 0; i < 128; i++) s += gexp[i0 + i] * emsg[(size_t)(i0 + i) * 256 + d];
    egp[b * 256 + d] = s;
}
__global__ void egfinal_f(const float* __restrict__ egp, const float* __restrict__ scal,
                          float* __restrict__ out) {
    const int d = threadIdx.x;
    float s = 0.0f;
    for (int b = 0; b < 64; b++) s += egp[b * 256 + d];
    out[d] = s * scal[0];
}

__global__ void wsbad_k(float* __restrict__ out) { out[3] = 9000.0f; }

// ---------------------------------------------------------------------------
extern "C" void kernel_launch(void* const* d_in, const int* in_sizes, int n_in,
                              void* d_out, int out_size, void* d_ws, size_t ws_size,
                              hipStream_t stream) {
    (void)in_sizes; (void)n_in; (void)out_size;
    const float* x_path = (const float*)d_in[0];
    const float* fc1_W  = (const float*)d_in[1];
    const float* fc1_b  = (const float*)d_in[2];
    const float* Wh     = (const float*)d_in[3];
    const float* bh     = (const float*)d_in[4];
    const float* Wt     = (const float*)d_in[5];
    const float* bt     = (const float*)d_in[6];
    const float* W1     = (const float*)d_in[7];
    const float* b1     = (const float*)d_in[8];
    const float* W2     = (const float*)d_in[9];
    const float* b2     = (const float*)d_in[10];
    const float* Ag1    = (const float*)d_in[11];
    const float* bg1    = (const float*)d_in[12];
    const float* Ag2    = (const float*)d_in[13];
    const float* bg2    = (const float*)d_in[14];
    float* out_f = (float*)d_out;   // fp32: e_msg [0,2097152), e_g [2097152,2097408)

    const size_t WS_NEEDED = 26412048;
    if (ws_size < WS_NEEDED) {
        hipLaunchKernelGGL(wsbad_k, dim3(1), dim3(1), 0, stream, out_f);
        return;
    }

    char* ws = (char*)d_ws;
    float* x     = (float*)(ws + 0);
    unsigned short* eh16 = (unsigned short*)(ws + 0);
    unsigned short* et16 = (unsigned short*)(ws + 4194304);
    unsigned short* m1b  = (unsigned short*)(ws + 0);
    unsigned short* m2b  = (unsigned short*)(ws + 4194304);
    float* g1    = (float*)(ws + 0);          // 8192x128 fp32 (after m1b/m2b dead)
    float* eh    = (float*)(ws + 8388608);
    float* emsg  = (float*)(ws + 8388608);
    float* et    = (float*)(ws + 16777216);
    int*   candi = (int*)  (ws + 25165824);
    float* meanp = (float*)(ws + 26214400);
    float* meanv = (float*)(ws + 26279936);
    float* glog  = (float*)(ws + 26280960);
    float* gexp  = (float*)(ws + 26313728);
    float* egp   = (float*)(ws + 26346496);
    float* scal  = (float*)(ws + 26412032);

    dim3 gg(4, 128);
    // 1) x = leaky(x_path @ fc1_W + fc1_b)
    hipLaunchKernelGGL((gemmV<0, 1, 0>), gg, dim3(256), 0, stream,
                       (const void*)x_path, fc1_W, fc1_b, x, 8192, 256, 1024);
    // 2) x = (x + mean(x)) * 0.5
    hipLaunchKernelGGL(colsum_k, dim3(64), dim3(256), 0, stream, x, meanp);
    hipLaunchKernelGGL(meanred_k, dim3(1), dim3(256), 0, stream, meanp, meanv);
    hipLaunchKernelGGL(finalize_x, dim3(2048), dim3(256), 0, stream, x, meanv);
    // 3) e_h, e_t (fp32 exact)
    hipLaunchKernelGGL((gemmV<0, 0, 0>), gg, dim3(256), 0, stream,
                       (const void*)x, Wh, bh, eh, 8192, 256, 256);
    hipLaunchKernelGGL((gemmV<0, 0, 0>), gg, dim3(256), 0, stream,
                       (const void*)x, Wt, bt, et, 8192, 256, 256);
    // 4) bf16 copies for screening
    hipLaunchKernelGGL(f2bf_k, dim3(2048), dim3(256), 0, stream, eh, eh16, 524288);
    hipLaunchKernelGGL(f2bf_k, dim3(2048), dim3(256), 0, stream, et, et16, 524288);
    // 5) screening: register top-6/lane -> merged top-8 per quarter -> 32 cand/row
    hipLaunchKernelGGL(screen2, dim3(4, 128), dim3(256), 0, stream, eh16, et16, candi);
    // 6) fp64 select + message -> m1b/m2b
    hipLaunchKernelGGL(stageD, dim3(8192), dim3(64), 0, stream, eh, et, candi, m1b, m2b);
    // 7) e_msg = leaky(m1@W1+b1) + leaky(m2@W2+b2)
    hipLaunchKernelGGL((gemmV<1, 1, 0>), gg, dim3(256), 0, stream,
                       (const void*)m1b, W1, b1, emsg, 8192, 256, 256);
    hipLaunchKernelGGL((gemmV<1, 1, 1>), gg, dim3(256), 0, stream,
                       (const void*)m2b, W2, b2, emsg, 8192, 256, 256);
    // 8) output 0: e_msg fp32
    hipLaunchKernelGGL(cpy_k, dim3(2048), dim3(256), 0, stream, emsg, out_f);
    // 9) readout: g1 = leaky(emsg@Ag1+bg1); glog = g1@Ag2+bg2; softmax; weighted sum
    hipLaunchKernelGGL((gemmV<0, 1, 0>), dim3(2, 128), dim3(256), 0, stream,
                       (const void*)emsg, Ag1, bg1, g1, 8192, 128, 256);
    hipLaunchKernelGGL(gate2_k, dim3(32), dim3(256), 0, stream, g1, Ag2, bg2, glog);
    hipLaunchKernelGGL(softmax_g, dim3(1), dim3(1024), 0, stream, glog, gexp, scal);
    hipLaunchKernelGGL(wsum_k, dim3(64), dim3(256), 0, stream, emsg, gexp, egp);
    hipLaunchKernelGGL(egfinal_f, dim3(1), dim3(256), 0, stream, egp, scal, out_f + 2097152);
}

// Round 3
// 443.116 us; speedup vs baseline: 1.2401x; 1.0438x over previous
//
#include <hip/hip_runtime.h>

// MOTCAT_Surv R13. R12 passed (absmax 0.0156, 462 us); stageD now the whale (99 us,
// MfmaUtil 0, VALUBusy 34%, Occ 41%, HBM 2.5%) -- latency-bound on serialized
// structure: 32x dependent fp64 shuffle-reduces, serial lane-0 top-6 (192 dependent
// fp64 cmps), 12-lane x 64-iter LDS colsum, 1-wave blocks. This round: stageD is
// rewritten LDS-free/barrier-free, 4 rows per 256-thr block: (a) candidate-parallel
// rescore (lane pair owns a candidate, 128-dim fp64 dot each, one shfl combine);
// (b) wave-parallel argmax top-6 (butterfly on (v,j), R9's exact comparator) with
// selj/w6/softmax register-resident on all lanes; (c) Nb_h.sum(-1) == e_t row-sum
// is i-independent -> precomputed rowsum[8192] (reuses dead meanp slot); gate.sum
// via 36-shuffle butterfly. Selection ordering semantics identical to R9.
// Everything else identical to R12.

typedef __attribute__((ext_vector_type(8))) short short8;
typedef __attribute__((ext_vector_type(4))) short short4v;
typedef __attribute__((ext_vector_type(4))) float f32x4;

__device__ inline float bf2f(unsigned short b) {
    unsigned u = ((unsigned)b) << 16;
    return __builtin_bit_cast(float, u);
}
__device__ inline unsigned short f2bf(float f) {   // round-to-nearest-even
    unsigned u = __builtin_bit_cast(unsigned, f);
    unsigned r = u + 0x7fffu + ((u >> 16) & 1u);
    return (unsigned short)(r >> 16);
}
__device__ inline f32x4 mfma16(short8 a, short8 b, f32x4 c) {
    return __builtin_amdgcn_mfma_f32_16x16x32_bf16(a, b, c, 0, 0, 0);
}
// A-frag: lane holds A[m=lane&15][k=(lane>>4)*8+j]; B-frag: B[k][n=lane&15];
// C/D: col=lane&15 (n), row=(lane>>4)*4+reg (m) (learn_hip m89).

// ---------------------------------------------------------------------------
// VALU fp32 GEMM (proven R9): C = act(A@B + bias) (+=C if ACCUM). 64x64 tile, BK=16.
// ---------------------------------------------------------------------------
template <int AISBF, int ACT, int ACCUM>
__launch_bounds__(256)
__global__ void gemmV(const void* __restrict__ Av, const float* __restrict__ B,
                      const float* __restrict__ bias, float* __restrict__ C,
                      int M, int N, int K) {
    __shared__ float As[64][17];
    __shared__ float Bs[16][68];
    const int t = threadIdx.x;
    const int row0 = blockIdx.y * 64, col0 = blockIdx.x * 64;
    const int tx = t & 15, ty = t >> 4;

    float acc[4][4];
    #pragma unroll
    for (int i = 0; i < 4; i++)
        #pragma unroll
        for (int j = 0; j < 4; j++) acc[i][j] = 0.0f;

    for (int kt = 0; kt < K; kt += 16) {
        {
            const int row = t >> 2, kq = (t & 3) * 4;
            if (AISBF) {
                const unsigned short* a16 = (const unsigned short*)Av;
                #pragma unroll
                for (int e = 0; e < 4; e++)
                    As[row][kq + e] = bf2f(a16[(size_t)(row0 + row) * K + kt + kq + e]);
            } else {
                const float* a32 = (const float*)Av;
                f32x4 v = *(const f32x4*)&a32[(size_t)(row0 + row) * K + kt + kq];
                #pragma unroll
                for (int e = 0; e < 4; e++) As[row][kq + e] = v[e];
            }
        }
        {
            const int k = t >> 4, n4 = (t & 15) * 4;
            f32x4 v = *(const f32x4*)&B[(size_t)(kt + k) * N + col0 + n4];
            #pragma unroll
            for (int e = 0; e < 4; e++) Bs[k][n4 + e] = v[e];
        }
        __syncthreads();
        #pragma unroll
        for (int kk = 0; kk < 16; kk++) {
            float a0 = As[ty * 4 + 0][kk], a1 = As[ty * 4 + 1][kk];
            float a2 = As[ty * 4 + 2][kk], a3 = As[ty * 4 + 3][kk];
            float b0 = Bs[kk][tx * 4 + 0], b1 = Bs[kk][tx * 4 + 1];
            float b2 = Bs[kk][tx * 4 + 2], b3 = Bs[kk][tx * 4 + 3];
            acc[0][0] += a0 * b0; acc[0][1] += a0 * b1; acc[0][2] += a0 * b2; acc[0][3] += a0 * b3;
            acc[1][0] += a1 * b0; acc[1][1] += a1 * b1; acc[1][2] += a1 * b2; acc[1][3] += a1 * b3;
            acc[2][0] += a2 * b0; acc[2][1] += a2 * b1; acc[2][2] += a2 * b2; acc[2][3] += a2 * b3;
            acc[3][0] += a3 * b0; acc[3][1] += a3 * b1; acc[3][2] += a3 * b2; acc[3][3] += a3 * b3;
        }
        __syncthreads();
    }
    #pragma unroll
    for (int i = 0; i < 4; i++) {
        const int row = row0 + ty * 4 + i;
        #pragma unroll
        for (int j = 0; j < 4; j++) {
            const int col = col0 + tx * 4 + j;
            float v = acc[i][j] + bias[col];
            if (ACT == 1) v = v > 0.0f ? v : 0.01f * v;
            size_t idx = (size_t)row * N + col;
            if (ACCUM) v += C[idx];
            C[idx] = v;
        }
    }
}

// ---------------------------------------------------------------------------
__global__ void colsum_k(const float* __restrict__ x, float* __restrict__ out) {
    int d = threadIdx.x, b = blockIdx.x;
    float s = 0.0f;
    int i0 = b * 128;
    for (int i = 0; i < 128; i++) s += x[(size_t)(i0 + i) * 256 + d];
    out[b * 256 + d] = s;
}
__global__ void meanred_k(const float* __restrict__ p, float* __restrict__ mean) {
    int d = threadIdx.x;
    float s = 0.0f;
    for (int b = 0; b < 64; b++) s += p[b * 256 + d];
    mean[d] = s * (1.0f / 8192.0f);
}
__global__ void finalize_x(float* __restrict__ x, const float* __restrict__ mean) {
    size_t idx = (size_t)blockIdx.x * blockDim.x + threadIdx.x;
    f32x4 v = *(f32x4*)&x[idx * 4];
    int d4 = (int)((idx * 4) & 255);
    f32x4 m = *(const f32x4*)&mean[d4];
    #pragma unroll
    for (int e = 0; e < 4; e++) v[e] = (v[e] + m[e]) * 0.5f;
    *(f32x4*)&x[idx * 4] = v;
}
__global__ void f2bf_k(const float* __restrict__ src, unsigned short* __restrict__ dst, int n4) {
    size_t idx = (size_t)blockIdx.x * blockDim.x + threadIdx.x;
    if (idx >= (size_t)n4) return;
    f32x4 v = *(const f32x4*)&src[idx * 4];
    short4v h;
    #pragma unroll
    for (int e = 0; e < 4; e++) h[e] = (short)f2bf(v[e]);
    *(short4v*)&dst[idx * 4] = h;
}
__global__ void cpy_k(const float* __restrict__ src, float* __restrict__ dst) {
    size_t idx = (size_t)blockIdx.x * blockDim.x + threadIdx.x;
    *(f32x4*)&dst[idx * 4] = *(const f32x4*)&src[idx * 4];
}
// rowsum[i] = sum_d et[i][d]  (Nb_h.sum(-1) is i-independent of the gather row)
__launch_bounds__(256)
__global__ void rowsum_k(const float* __restrict__ et, float* __restrict__ rowsum) {
    const int w = threadIdx.x >> 6, l = threadIdx.x & 63;
    const int i = blockIdx.x * 4 + w;
    f32x4 v = *(const f32x4*)&et[(size_t)i * 256 + l * 4];
    float s = v[0] + v[1] + v[2] + v[3];
    #pragma unroll
    for (int st = 1; st < 64; st <<= 1) s += __shfl_xor(s, st);
    if (l == 0) rowsum[i] = s;
}

// ---------------------------------------------------------------------------
// screen2 helpers: monotone fp32->uint key; branchless sorted-insert (ascending,
// tk[0]=min). med3 identity: tk[k] = max(min(key, tk[k+1]), tk[k]) -- 2 VALU/slot.
// ---------------------------------------------------------------------------
__device__ inline unsigned fkey(float f) {
    unsigned u = __builtin_bit_cast(unsigned, f);
    unsigned s = (unsigned)((int)u >> 31);          // 0 or 0xFFFFFFFF
    return u ^ (s | 0x80000000u);                   // order-preserving
}
template<int NK>
__device__ inline void ins(unsigned (&tk)[NK], unsigned key) {
    #pragma unroll
    for (int k = 0; k < NK - 1; k++) {
        unsigned lo = key < tk[k + 1] ? key : tk[k + 1];
        tk[k] = lo > tk[k] ? lo : tk[k];
    }
    tk[NK - 1] = key > tk[NK - 1] ? key : tk[NK - 1];
}
__device__ inline void gload_lds16(const unsigned short* g, unsigned short* l) {
    __builtin_amdgcn_global_load_lds(
        (const __attribute__((address_space(1))) void*)g,
        (__attribute__((address_space(3))) void*)l, 16, 0, 0);
}

// ---------------------------------------------------------------------------
// screen2 (proven R12): swapped MFMA, single branchless top-6 queue/lane, 2-step
// butterfly merge -> top-8 per quarter. XOR-swizzled double-buffered LDS staging.
// ---------------------------------------------------------------------------
__launch_bounds__(256)
__global__ void screen2(const unsigned short* __restrict__ eh16,
                        const unsigned short* __restrict__ et16,
                        int* __restrict__ candi) {
    __shared__ __align__(16) unsigned short Bs[2][8192];   // 2 x (32 cols x 256 k)
    const int t = threadIdx.x;
    const int cs = blockIdx.x;
    const int r0 = blockIdx.y * 64;
    const int w = t >> 6, lid = t & 63, g = lid >> 4, m16 = lid & 15;
    const int ar = w * 16;

    short8 bfr[8];   // eh B-frags: lane's row = r0+ar+m16, k = ks*32 + g*8 + j
    #pragma unroll
    for (int ks = 0; ks < 8; ks++)
        bfr[ks] = *(const short8*)&eh16[(size_t)(r0 + ar + m16) * 256 + ks * 32 + g * 8];

    unsigned tk[6];
    #pragma unroll
    for (int q = 0; q < 6; q++) tk[q] = 0u;

    int scol[4], goff[4], ldsl[4];
    #pragma unroll
    for (int c = 0; c < 4; c++) {
        int L = (w * 4 + c) * 64 + lid;
        int col = L >> 5, gs = L & 31;
        int gorig = (gs & 24) | ((gs ^ col) & 7);
        scol[c] = col; goff[c] = gorig * 8; ldsl[c] = L * 8;
    }

    #pragma unroll
    for (int c = 0; c < 4; c++)
        gload_lds16(&et16[(size_t)(cs * 2048 + scol[c]) * 256 + goff[c]], &Bs[0][ldsl[c]]);
    __syncthreads();

    const int swz = m16 & 7;
    for (int tile = 0; tile < 64; tile++) {
        const int cur = tile & 1;
        if (tile + 1 < 64) {
            const int j1 = cs * 2048 + (tile + 1) * 32;
            #pragma unroll
            for (int c = 0; c < 4; c++)
                gload_lds16(&et16[(size_t)(j1 + scol[c]) * 256 + goff[c]],
                            &Bs[cur ^ 1][ldsl[c]]);
        }
        f32x4 a0 = {0.0f, 0.0f, 0.0f, 0.0f}, a1 = a0;
        #pragma unroll
        for (int ks = 0; ks < 8; ks++) {
            const int gq = ks * 4 + g;
            short8 e0 = *(const short8*)&Bs[cur][(m16 * 32 + (gq ^ swz)) * 8];
            short8 e1 = *(const short8*)&Bs[cur][((16 + m16) * 32 + (gq ^ swz)) * 8];
            a0 = mfma16(e0, bfr[ks], a0);   // swapped: A = et (LDS), B = eh (regs)
            a1 = mfma16(e1, bfr[ks], a1);
        }
        const unsigned cb = (unsigned)(tile * 32 + g * 4);
        #pragma unroll
        for (int r = 0; r < 4; r++) {
            ins<6>(tk, (fkey(a0[r]) & 0xFFFFF800u) | (cb + (unsigned)r));
            ins<6>(tk, (fkey(a1[r]) & 0xFFFFF800u) | (cb + 16u + (unsigned)r));
        }
        __syncthreads();
    }

    unsigned tk8[8];
    tk8[0] = 0u; tk8[1] = 0u;
    #pragma unroll
    for (int q = 0; q < 6; q++) tk8[q + 2] = tk[q];
    #pragma unroll
    for (int step = 16; step <= 32; step <<= 1) {
        unsigned ok[8];
        #pragma unroll
        for (int q = 0; q < 8; q++) ok[q] = (unsigned)__shfl_xor((int)tk8[q], step);
        #pragma unroll
        for (int q = 0; q < 8; q++) ins<8>(tk8, ok[q]);
    }
    if (g == 0) {
        const int row = r0 + ar + m16;
        #pragma unroll
        for (int q = 0; q < 8; q++)
            candi[(size_t)row * 32 + cs * 8 + q] = cs * 2048 + (int)(tk8[q] & 0x7FFu);
    }
}

// ---------------------------------------------------------------------------
// Stage D R13: LDS-free, barrier-free. 256 thr = 4 waves, one row per wave.
// Phase 1: lane pair (2c,2c+1) rescores candidate c (128-dim fp64 dot each half,
// one shfl combine). Phase 2: top-6 via 6 rounds of 6-step (v,j) butterfly argmax
// (R9 comparator: v>best || (v==best && j<bj)); all lanes end holding selj/w6 in
// registers -> softmax p redundant per-lane. Phase 3: per-lane d-slice message;
// gate.sum via 36-shuffle butterfly; Nb_h.sum from precomputed rowsum gather.
// ---------------------------------------------------------------------------
__launch_bounds__(256)
__global__ void stageD(const float* __restrict__ eh, const float* __restrict__ et,
                       const float* __restrict__ rowsum,
                       const int* __restrict__ candi,
                       unsigned short* __restrict__ m1, unsigned short* __restrict__ m2) {
    const int w = threadIdx.x >> 6, l = threadIdx.x & 63;
    const int i = blockIdx.x * 4 + w;

    // lane owns candidate (l&31)
    const int jown = candi[(size_t)i * 32 + (l & 31)] & 8191;

    // ---- phase 1: fp64 rescore, pair-split halves ----
    const int c = l >> 1, h = l & 1;
    const int jc = __shfl(jown, c);                  // candidate c's column
    const float* eprow = &eh[(size_t)i * 256 + h * 128];
    const float* etrow = &et[(size_t)jc * 256 + h * 128];
    double acc = 0.0, acc2 = 0.0;
    #pragma unroll 4
    for (int q = 0; q < 32; q += 2) {
        f32x4 a0 = *(const f32x4*)&eprow[q * 4];
        f32x4 b0 = *(const f32x4*)&etrow[q * 4];
        f32x4 a1 = *(const f32x4*)&eprow[q * 4 + 4];
        f32x4 b1 = *(const f32x4*)&etrow[q * 4 + 4];
        acc  += (double)a0[0] * b0[0] + (double)a0[1] * b0[1] +
                (double)a0[2] * b0[2] + (double)a0[3] * b0[3];
        acc2 += (double)a1[0] * b1[0] + (double)a1[1] * b1[1] +
                (double)a1[2] * b1[2] + (double)a1[3] * b1[3];
    }
    double p = acc + acc2;
    p += __shfl_xor(p, 1);                           // combine halves
    p *= 0.0625;

    // redistribute: lane l holds v = dot of candidate (l&31)
    double v = __shfl(p, 2 * (l & 31));

    // ---- phase 2: top-6 argmax butterflies (all lanes converge) ----
    float wf[6]; int selj[6];
    #pragma unroll
    for (int s = 0; s < 6; s++) {
        double bv = v; int bj = jown;
        #pragma unroll
        for (int st = 1; st < 64; st <<= 1) {
            double ov = __shfl_xor(bv, st);
            int oj = __shfl_xor(bj, st);
            bool take = (ov > bv) || (ov == bv && oj < bj);
            bv = take ? ov : bv;
            bj = take ? oj : bj;
        }
        wf[s] = (float)bv; selj[s] = bj;
        if (jown == bj) v = -1.0e300;                // kill selected candidate
    }

    // softmax over the 6 selected logits (redundant per-lane, register-resident)
    float sp[6];
    {
        float mx = wf[0];
        #pragma unroll
        for (int s = 1; s < 6; s++) mx = fmaxf(mx, wf[s]);
        float se = 0.0f, e6[6];
        #pragma unroll
        for (int s = 0; s < 6; s++) { e6[s] = expf(wf[s] - mx); se += e6[s]; }
        #pragma unroll
        for (int s = 0; s < 6; s++) sp[s] = e6[s] / se;
    }

    // ---- phase 3: message construction, per-lane d-slice ----
    f32x4 eh4 = *(const f32x4*)&eh[(size_t)i * 256 + l * 4];
    f32x4 nb[6];
    #pragma unroll
    for (int k = 0; k < 6; k++)
        nb[k] = *(const f32x4*)&et[(size_t)selj[k] * 256 + l * 4];

    float pgs[6], pns[6];
    #pragma unroll
    for (int k = 0; k < 6; k++) {
        const float pk = sp[k];
        float pg = 0.0f;
        #pragma unroll
        for (int e = 0; e < 4; e++) {
            float ehd = eh4[e], nbd = nb[k][e];
            float ehr = pk * nbd + (1.0f - pk) * ehd;
            pg += tanhf(ehd + ehr);
        }
        #pragma unroll
        for (int st = 1; st < 64; st <<= 1) pg += __shfl_xor(pg, st);
        pgs[k] = pg;
        pns[k] = rowsum[selj[k]];
    }

    // ka softmax (redundant per-lane)
    float skp[6];
    {
        float ka[6], mx = -3.0e38f, se = 0.0f;
        #pragma unroll
        for (int k = 0; k < 6; k++) { ka[k] = pns[k] * pgs[k]; mx = fmaxf(mx, ka[k]); }
        #pragma unroll
        for (int k = 0; k < 6; k++) { ka[k] = expf(ka[k] - mx); se += ka[k]; }
        #pragma unroll
        for (int k = 0; k < 6; k++) skp[k] = ka[k] / se;
    }

    f32x4 enh = {0.0f, 0.0f, 0.0f, 0.0f};
    #pragma unroll
    for (int k = 0; k < 6; k++) {
        const float kp = skp[k];
        #pragma unroll
        for (int e = 0; e < 4; e++) enh[e] += kp * nb[k][e];
    }
    short4v h1, h2;
    #pragma unroll
    for (int e = 0; e < 4; e++) {
        h1[e] = (short)f2bf(eh4[e] + enh[e]);
        h2[e] = (short)f2bf(eh4[e] * enh[e]);
    }
    *(short4v*)&m1[(size_t)i * 256 + l * 4] = h1;
    *(short4v*)&m2[(size_t)i * 256 + l * 4] = h2;
}

// ---------------------------------------------------------------------------
// Readout: g1 = leaky(emsg@Ag1+bg1) via gemmV; then glog = g1@Ag2 + bg2.
// ---------------------------------------------------------------------------
__launch_bounds__(256)
__global__ void gate2_k(const float* __restrict__ g1, const float* __restrict__ Ag2,
                        const float* __restrict__ bg2, float* __restrict__ glog) {
    const int i = blockIdx.x * 256 + threadIdx.x;
    float s = 0.0f;
    #pragma unroll 4
    for (int h = 0; h < 128; h++) s += g1[(size_t)i * 128 + h] * Ag2[h];
    glog[i] = s + bg2[0];
}

__launch_bounds__(1024)
__global__ void softmax_g(const float* __restrict__ glog, float* __restrict__ gexp,
                          float* __restrict__ scal) {
    const int t = threadIdx.x;
    __shared__ float red[1024];
    float v[8];
    float m = -3.0e38f;
    #pragma unroll
    for (int c = 0; c < 8; c++) { v[c] = glog[t + c * 1024]; m = fmaxf(m, v[c]); }
    red[t] = m; __syncthreads();
    for (int st = 512; st > 0; st >>= 1) {
        if (t < st) red[t] = fmaxf(red[t], red[t + st]);
        __syncthreads();
    }
    float gm = red[0]; __syncthreads();
    float s = 0.0f;
    #pragma unroll
    for (int c = 0; c < 8; c++) {
        float e = expf(v[c] - gm);
        gexp[t + c * 1024] = e;
        s += e;
    }
    red[t] = s; __syncthreads();
    for (int st = 512; st > 0; st >>= 1) {
        if (t < st) red[t] += red[t + st];
        __syncthreads();
    }
    if (t == 0) scal[0] = 1.0f / red[0];
}

__launch_bounds__(256)
__global__ void wsum_k(const float* __restrict__ emsg, const float* __restrict__ gexp,
                       float* __restrict__ egp) {
    const int b = blockIdx.x, d = threadIdx.x;
    float s = 0.0f;
    const int i0 = b * 128;
    for (int i = 0; i < 128; i++) s += gexp[i0 + i] * emsg[(size_t)(i0 + i) * 256 + d];
    egp[b * 256 + d] = s;
}
__global__ void egfinal_f(const float* __restrict__ egp, const float* __restrict__ scal,
                          float* __restrict__ out) {
    const int d = threadIdx.x;
    float s = 0.0f;
    for (int b = 0; b < 64; b++) s += egp[b * 256 + d];
    out[d] = s * scal[0];
}

__global__ void wsbad_k(float* __restrict__ out) { out[3] = 9000.0f; }

// ---------------------------------------------------------------------------
extern "C" void kernel_launch(void* const* d_in, const int* in_sizes, int n_in,
                              void* d_out, int out_size, void* d_ws, size_t ws_size,
                              hipStream_t stream) {
    (void)in_sizes; (void)n_in; (void)out_size;
    const float* x_path = (const float*)d_in[0];
    const float* fc1_W  = (const float*)d_in[1];
    const float* fc1_b  = (const float*)d_in[2];
    const float* Wh     = (const float*)d_in[3];
    const float* bh     = (const float*)d_in[4];
    const float* Wt     = (const float*)d_in[5];
    const float* bt     = (const float*)d_in[6];
    const float* W1     = (const float*)d_in[7];
    const float* b1     = (const float*)d_in[8];
    const float* W2     = (const float*)d_in[9];
    const float* b2     = (const float*)d_in[10];
    const float* Ag1    = (const float*)d_in[11];
    const float* bg1    = (const float*)d_in[12];
    const float* Ag2    = (const float*)d_in[13];
    const float* bg2    = (const float*)d_in[14];
    float* out_f = (float*)d_out;   // fp32: e_msg [0,2097152), e_g [2097152,2097408)

    const size_t WS_NEEDED = 26412048;
    if (ws_size < WS_NEEDED) {
        hipLaunchKernelGGL(wsbad_k, dim3(1), dim3(1), 0, stream, out_f);
        return;
    }

    char* ws = (char*)d_ws;
    float* x     = (float*)(ws + 0);
    unsigned short* eh16 = (unsigned short*)(ws + 0);
    unsigned short* et16 = (unsigned short*)(ws + 4194304);
    unsigned short* m1b  = (unsigned short*)(ws + 0);
    unsigned short* m2b  = (unsigned short*)(ws + 4194304);
    float* g1    = (float*)(ws + 0);          // 8192x128 fp32 (after m1b/m2b dead)
    float* eh    = (float*)(ws + 8388608);
    float* emsg  = (float*)(ws + 8388608);
    float* et    = (float*)(ws + 16777216);
    int*   candi = (int*)  (ws + 25165824);
    float* meanp = (float*)(ws + 26214400);   // dead after meanred -> reused as rowsum
    float* rowsum= (float*)(ws + 26214400);
    float* meanv = (float*)(ws + 26279936);
    float* glog  = (float*)(ws + 26280960);
    float* gexp  = (float*)(ws + 26313728);
    float* egp   = (float*)(ws + 26346496);
    float* scal  = (float*)(ws + 26412032);

    dim3 gg(4, 128);
    // 1) x = leaky(x_path @ fc1_W + fc1_b)
    hipLaunchKernelGGL((gemmV<0, 1, 0>), gg, dim3(256), 0, stream,
                       (const void*)x_path, fc1_W, fc1_b, x, 8192, 256, 1024);
    // 2) x = (x + mean(x)) * 0.5
    hipLaunchKernelGGL(colsum_k, dim3(64), dim3(256), 0, stream, x, meanp);
    hipLaunchKernelGGL(meanred_k, dim3(1), dim3(256), 0, stream, meanp, meanv);
    hipLaunchKernelGGL(finalize_x, dim3(2048), dim3(256), 0, stream, x, meanv);
    // 3) e_h, e_t (fp32 exact)
    hipLaunchKernelGGL((gemmV<0, 0, 0>), gg, dim3(256), 0, stream,
                       (const void*)x, Wh, bh, eh, 8192, 256, 256);
    hipLaunchKernelGGL((gemmV<0, 0, 0>), gg, dim3(256), 0, stream,
                       (const void*)x, Wt, bt, et, 8192, 256, 256);
    // 4) bf16 copies for screening + et row sums
    hipLaunchKernelGGL(f2bf_k, dim3(2048), dim3(256), 0, stream, eh, eh16, 524288);
    hipLaunchKernelGGL(f2bf_k, dim3(2048), dim3(256), 0, stream, et, et16, 524288);
    hipLaunchKernelGGL(rowsum_k, dim3(2048), dim3(256), 0, stream, et, rowsum);
    // 5) screening: register top-6/lane -> merged top-8 per quarter -> 32 cand/row
    hipLaunchKernelGGL(screen2, dim3(4, 128), dim3(256), 0, stream, eh16, et16, candi);
    // 6) fp64 select + message -> m1b/m2b (4 rows per block)
    hipLaunchKernelGGL(stageD, dim3(2048), dim3(256), 0, stream, eh, et, rowsum,
                       candi, m1b, m2b);
    // 7) e_msg = leaky(m1@W1+b1) + leaky(m2@W2+b2)
    hipLaunchKernelGGL((gemmV<1, 1, 0>), gg, dim3(256), 0, stream,
                       (const void*)m1b, W1, b1, emsg, 8192, 256, 256);
    hipLaunchKernelGGL((gemmV<1, 1, 1>), gg, dim3(256), 0, stream,
                       (const void*)m2b, W2, b2, emsg, 8192, 256, 256);
    // 8) output 0: e_msg fp32
    hipLaunchKernelGGL(cpy_k, dim3(2048), dim3(256), 0, stream, emsg, out_f);
    // 9) readout: g1 = leaky(emsg@Ag1+bg1); glog = g1@Ag2+bg2; softmax; weighted sum
    hipLaunchKernelGGL((gemmV<0, 1, 0>), dim3(2, 128), dim3(256), 0, stream,
                       (const void*)emsg, Ag1, bg1, g1, 8192, 128, 256);
    hipLaunchKernelGGL(gate2_k, dim3(32), dim3(256), 0, stream, g1, Ag2, bg2, glog);
    hipLaunchKernelGGL(softmax_g, dim3(1), dim3(1024), 0, stream, glog, gexp, scal);
    hipLaunchKernelGGL(wsum_k, dim3(64), dim3(256), 0, stream, emsg, gexp, egp);
    hipLaunchKernelGGL(egfinal_f, dim3(1), dim3(256), 0, stream, egp, scal, out_f + 2097152);
}

// Round 5
// 377.261 us; speedup vs baseline: 1.4566x; 1.1746x over previous
//
#include <hip/hip_runtime.h>

// MOTCAT_Surv R15 (= R14 resubmitted; previous bench died to container infra,
// no kernel verdict). R13 passed (absmax 0.0156, 443 us); fc1 gemmV is the whale
// (91 us, MfmaUtil 0, VALUBusy 33%, occ 19%) and the other 4 gemmVs add ~95 us.
// This round replaces ALL GEMMs with MFMA split-bf16 (gemmM): fp32 operands are
// 3-way bf16-split (hi+mid+lo, residual 2^-26) and C = 6 products (hh,hm,mh,hl,
// mm,lh) accumulated fp32 -> fp32-level accuracy, selection statistics unchanged.
// W1/W2 (A already bf16) use a 2-product B-split (numerically = old path).
// Weights are transpose-split once (tsplit3, LDS 32x32 transpose) into bf16
// planes Bt[n][k] placed in temporarily-dead ws regions (et region / candi
// region) -- WS_NEEDED unchanged; all aliasing is stream-ordered-safe.
// gemmM: 64x64 tile, BK=32, 4 waves (32x32 each, 2x2 frags), A split on-the-fly
// (reg load early, cvt+ds_write late), B via global_load_lds, double-buffered,
// 1 barrier/K-step. Granule layout row*64B + g*16B puts all frag reads/writes
// at the 8-lane/bank-quad b128 floor (no swizzle).
// screen2/stageD/readout identical to R13 (proven).

typedef __attribute__((ext_vector_type(8))) short short8;
typedef __attribute__((ext_vector_type(4))) short short4v;
typedef __attribute__((ext_vector_type(4))) float f32x4;

__device__ inline float bf2f(unsigned short b) {
    unsigned u = ((unsigned)b) << 16;
    return __builtin_bit_cast(float, u);
}
__device__ inline unsigned short f2bf(float f) {   // round-to-nearest-even
    unsigned u = __builtin_bit_cast(unsigned, f);
    unsigned r = u + 0x7fffu + ((u >> 16) & 1u);
    return (unsigned short)(r >> 16);
}
__device__ inline f32x4 mfma16(short8 a, short8 b, f32x4 c) {
    return __builtin_amdgcn_mfma_f32_16x16x32_bf16(a, b, c, 0, 0, 0);
}
// A-frag: lane holds A[m=lane&15][k=(lane>>4)*8+j]; B-frag: B[k][n=lane&15];
// C/D: col=lane&15 (n), row=(lane>>4)*4+reg (m) (learn_hip m89).

__device__ inline void gload_lds16(const unsigned short* g, unsigned short* l) {
    __builtin_amdgcn_global_load_lds(
        (const __attribute__((address_space(1))) void*)g,
        (__attribute__((address_space(3))) void*)l, 16, 0, 0);
}

// split fp32 -> bf16 hi/mid/lo (residual subtractions are exact: operands close)
__device__ inline void split8(const f32x4 v0, const f32x4 v1,
                              short8& hi, short8& md, short8& lo) {
    #pragma unroll
    for (int e = 0; e < 8; e++) {
        float a = (e < 4) ? v0[e] : v1[e - 4];
        unsigned short h = f2bf(a);
        float r1 = a - bf2f(h);
        unsigned short m = f2bf(r1);
        float r2 = r1 - bf2f(m);
        unsigned short l = f2bf(r2);
        hi[e] = (short)h; md[e] = (short)m; lo[e] = (short)l;
    }
}

// ---------------------------------------------------------------------------
// tsplit3: W [K][N] fp32 -> Bt planes [n][k] bf16 (hi, mid, lo) at out + p*PS.
// 32x32 LDS transpose tile; grid (N/32, K/32), 256 thr.
// ---------------------------------------------------------------------------
__launch_bounds__(256)
__global__ void tsplit3(const float* __restrict__ W, unsigned short* __restrict__ out,
                        int K, int N, int PS) {
    __shared__ float T[32][33];
    const int t = threadIdx.x;
    const int n0 = blockIdx.x * 32, k0 = blockIdx.y * 32;
    {
        const int r = t >> 3, c = (t & 7) * 4;
        f32x4 v = *(const f32x4*)&W[(size_t)(k0 + r) * N + n0 + c];
        #pragma unroll
        for (int e = 0; e < 4; e++) T[r][c + e] = v[e];
    }
    __syncthreads();
    const int nr = t >> 3, kc = (t & 7) * 4;
    short4v h4, m4, l4;
    #pragma unroll
    for (int e = 0; e < 4; e++) {
        float a = T[kc + e][nr];
        unsigned short h = f2bf(a);
        float r1 = a - bf2f(h);
        unsigned short m = f2bf(r1);
        float r2 = r1 - bf2f(m);
        h4[e] = (short)h; m4[e] = (short)m; l4[e] = (short)f2bf(r2);
    }
    const size_t o = (size_t)(n0 + nr) * K + k0 + kc;
    *(short4v*)&out[o] = h4;
    *(short4v*)&out[(size_t)PS + o] = m4;
    *(short4v*)&out[(size_t)2 * PS + o] = l4;
}

// ---------------------------------------------------------------------------
// gemmM: C = act(A@B + bias) (+=C if ACCUM) on matrix cores.
// ASPLIT=1: A fp32, 3-plane on-the-fly split, 6 products (fp32-accurate).
// ASPLIT=0: A bf16 (global), B 2-plane, 2 products.
// B from pre-split planes Bt[n][k] (stride BPS elems). 64x64 tile, BK=32,
// 256 thr = 4 waves (2x2), wave tile 32x32 = 2x2 fragments. Double-buffered,
// one barrier per K-step.
// ---------------------------------------------------------------------------
template <int ASPLIT, int ACT, int ACCUM>
__launch_bounds__(256)
__global__ void gemmM(const void* __restrict__ Av,
                      const unsigned short* __restrict__ Bt,
                      const float* __restrict__ bias, float* __restrict__ C,
                      int N, int K, int BPS) {
    constexpr int APL = ASPLIT ? 3 : 1;
    constexpr int BPL = ASPLIT ? 3 : 2;
    __shared__ __align__(16) unsigned short LA[2][APL * 2048];
    __shared__ __align__(16) unsigned short LB[2][BPL * 2048];
    const int t = threadIdx.x;
    const int r0 = blockIdx.y * 64, c0 = blockIdx.x * 64;
    const int lid = t & 63, w = t >> 6, g = lid >> 4, m16 = lid & 15;
    const int wm = w >> 1, wn = w & 1;

    f32x4 acc[2][2];
    #pragma unroll
    for (int mf = 0; mf < 2; mf++)
        #pragma unroll
        for (int nf = 0; nf < 2; nf++) acc[mf][nf] = {0.0f, 0.0f, 0.0f, 0.0f};

    const int KT = K >> 5;
    // staging: thread t owns row/col (t>>2), k-granule (t&3); LDS granule = 8*t
    const size_t aoff = (size_t)(r0 + (t >> 2)) * K + (t & 3) * 8;
    const size_t boff = (size_t)(c0 + (t >> 2)) * K + (t & 3) * 8;

    // prologue: stage k-step 0 into buf 0
    {
        #pragma unroll
        for (int p = 0; p < BPL; p++)
            gload_lds16(&Bt[(size_t)p * BPS + boff], &LB[0][p * 2048 + 8 * t]);
        if (ASPLIT) {
            const float* A = (const float*)Av;
            f32x4 v0 = *(const f32x4*)&A[aoff];
            f32x4 v1 = *(const f32x4*)&A[aoff + 4];
            short8 hi, md, lo;
            split8(v0, v1, hi, md, lo);
            *(short8*)&LA[0][8 * t] = hi;
            *(short8*)&LA[0][2048 + 8 * t] = md;
            *(short8*)&LA[0][4096 + 8 * t] = lo;
        } else {
            const unsigned short* A16 = (const unsigned short*)Av;
            gload_lds16(&A16[aoff], &LA[0][8 * t]);
        }
    }
    __syncthreads();

    for (int kt = 0; kt < KT; kt++) {
        const int cur = kt & 1, nxt = cur ^ 1;
        const bool hn = (kt + 1) < KT;
        f32x4 v0, v1;
        if (hn) {   // issue next-tile loads early
            const size_t ko = (size_t)(kt + 1) * 32;
            #pragma unroll
            for (int p = 0; p < BPL; p++)
                gload_lds16(&Bt[(size_t)p * BPS + boff + ko],
                            &LB[nxt][p * 2048 + 8 * t]);
            if (ASPLIT) {
                const float* A = (const float*)Av;
                v0 = *(const f32x4*)&A[aoff + ko];
                v1 = *(const f32x4*)&A[aoff + ko + 4];
            } else {
                const unsigned short* A16 = (const unsigned short*)Av;
                gload_lds16(&A16[aoff + ko], &LA[nxt][8 * t]);
            }
        }
        // compute on cur
        short8 af[2][APL], bf[2][BPL];
        #pragma unroll
        for (int mf = 0; mf < 2; mf++) {
            const int row = wm * 32 + mf * 16 + m16;
            #pragma unroll
            for (int p = 0; p < APL; p++)
                af[mf][p] = *(const short8*)&LA[cur][p * 2048 + row * 32 + g * 8];
        }
        #pragma unroll
        for (int nf = 0; nf < 2; nf++) {
            const int col = wn * 32 + nf * 16 + m16;
            #pragma unroll
            for (int p = 0; p < BPL; p++)
                bf[nf][p] = *(const short8*)&LB[cur][p * 2048 + col * 32 + g * 8];
        }
        #pragma unroll
        for (int mf = 0; mf < 2; mf++)
            #pragma unroll
            for (int nf = 0; nf < 2; nf++) {
                if (ASPLIT) {
                    acc[mf][nf] = mfma16(af[mf][0], bf[nf][0], acc[mf][nf]); // hh
                    acc[mf][nf] = mfma16(af[mf][0], bf[nf][1], acc[mf][nf]); // hm
                    acc[mf][nf] = mfma16(af[mf][1], bf[nf][0], acc[mf][nf]); // mh
                    acc[mf][nf] = mfma16(af[mf][0], bf[nf][2], acc[mf][nf]); // hl
                    acc[mf][nf] = mfma16(af[mf][1], bf[nf][1], acc[mf][nf]); // mm
                    acc[mf][nf] = mfma16(af[mf][2], bf[nf][0], acc[mf][nf]); // lh
                } else {
                    acc[mf][nf] = mfma16(af[mf][0], bf[nf][0], acc[mf][nf]);
                    acc[mf][nf] = mfma16(af[mf][0], bf[nf][1], acc[mf][nf]);
                }
            }
        if (hn && ASPLIT) {   // convert + write A next (loads have landed by now)
            short8 hi, md, lo;
            split8(v0, v1, hi, md, lo);
            *(short8*)&LA[nxt][8 * t] = hi;
            *(short8*)&LA[nxt][2048 + 8 * t] = md;
            *(short8*)&LA[nxt][4096 + 8 * t] = lo;
        }
        __syncthreads();
    }

    // epilogue
    #pragma unroll
    for (int nf = 0; nf < 2; nf++) {
        const int col = c0 + wn * 32 + nf * 16 + m16;
        const float bv = bias[col];
        #pragma unroll
        for (int mf = 0; mf < 2; mf++) {
            #pragma unroll
            for (int r = 0; r < 4; r++) {
                const int row = r0 + wm * 32 + mf * 16 + g * 4 + r;
                float v = acc[mf][nf][r] + bv;
                if (ACT == 1) v = v > 0.0f ? v : 0.01f * v;
                size_t idx = (size_t)row * N + col;
                if (ACCUM) v += C[idx];
                C[idx] = v;
            }
        }
    }
}

// ---------------------------------------------------------------------------
__global__ void colsum_k(const float* __restrict__ x, float* __restrict__ out) {
    int d = threadIdx.x, b = blockIdx.x;
    float s = 0.0f;
    int i0 = b * 128;
    for (int i = 0; i < 128; i++) s += x[(size_t)(i0 + i) * 256 + d];
    out[b * 256 + d] = s;
}
__global__ void meanred_k(const float* __restrict__ p, float* __restrict__ mean) {
    int d = threadIdx.x;
    float s = 0.0f;
    for (int b = 0; b < 64; b++) s += p[b * 256 + d];
    mean[d] = s * (1.0f / 8192.0f);
}
__global__ void finalize_x(float* __restrict__ x, const float* __restrict__ mean) {
    size_t idx = (size_t)blockIdx.x * blockDim.x + threadIdx.x;
    f32x4 v = *(f32x4*)&x[idx * 4];
    int d4 = (int)((idx * 4) & 255);
    f32x4 m = *(const f32x4*)&mean[d4];
    #pragma unroll
    for (int e = 0; e < 4; e++) v[e] = (v[e] + m[e]) * 0.5f;
    *(f32x4*)&x[idx * 4] = v;
}
__global__ void f2bf_k(const float* __restrict__ src, unsigned short* __restrict__ dst, int n4) {
    size_t idx = (size_t)blockIdx.x * blockDim.x + threadIdx.x;
    if (idx >= (size_t)n4) return;
    f32x4 v = *(const f32x4*)&src[idx * 4];
    short4v h;
    #pragma unroll
    for (int e = 0; e < 4; e++) h[e] = (short)f2bf(v[e]);
    *(short4v*)&dst[idx * 4] = h;
}
__global__ void cpy_k(const float* __restrict__ src, float* __restrict__ dst) {
    size_t idx = (size_t)blockIdx.x * blockDim.x + threadIdx.x;
    *(f32x4*)&dst[idx * 4] = *(const f32x4*)&src[idx * 4];
}
// rowsum[i] = sum_d et[i][d]
__launch_bounds__(256)
__global__ void rowsum_k(const float* __restrict__ et, float* __restrict__ rowsum) {
    const int w = threadIdx.x >> 6, l = threadIdx.x & 63;
    const int i = blockIdx.x * 4 + w;
    f32x4 v = *(const f32x4*)&et[(size_t)i * 256 + l * 4];
    float s = v[0] + v[1] + v[2] + v[3];
    #pragma unroll
    for (int st = 1; st < 64; st <<= 1) s += __shfl_xor(s, st);
    if (l == 0) rowsum[i] = s;
}

// ---------------------------------------------------------------------------
// screen2 helpers (proven R12)
// ---------------------------------------------------------------------------
__device__ inline unsigned fkey(float f) {
    unsigned u = __builtin_bit_cast(unsigned, f);
    unsigned s = (unsigned)((int)u >> 31);
    return u ^ (s | 0x80000000u);
}
template<int NK>
__device__ inline void ins(unsigned (&tk)[NK], unsigned key) {
    #pragma unroll
    for (int k = 0; k < NK - 1; k++) {
        unsigned lo = key < tk[k + 1] ? key : tk[k + 1];
        tk[k] = lo > tk[k] ? lo : tk[k];
    }
    tk[NK - 1] = key > tk[NK - 1] ? key : tk[NK - 1];
}

// ---------------------------------------------------------------------------
// screen2 (proven R12): swapped MFMA, single branchless top-6 queue/lane, 2-step
// butterfly merge -> top-8 per quarter. XOR-swizzled double-buffered LDS staging.
// ---------------------------------------------------------------------------
__launch_bounds__(256)
__global__ void screen2(const unsigned short* __restrict__ eh16,
                        const unsigned short* __restrict__ et16,
                        int* __restrict__ candi) {
    __shared__ __align__(16) unsigned short Bs[2][8192];
    const int t = threadIdx.x;
    const int cs = blockIdx.x;
    const int r0 = blockIdx.y * 64;
    const int w = t >> 6, lid = t & 63, g = lid >> 4, m16 = lid & 15;
    const int ar = w * 16;

    short8 bfr[8];
    #pragma unroll
    for (int ks = 0; ks < 8; ks++)
        bfr[ks] = *(const short8*)&eh16[(size_t)(r0 + ar + m16) * 256 + ks * 32 + g * 8];

    unsigned tk[6];
    #pragma unroll
    for (int q = 0; q < 6; q++) tk[q] = 0u;

    int scol[4], goff[4], ldsl[4];
    #pragma unroll
    for (int c = 0; c < 4; c++) {
        int L = (w * 4 + c) * 64 + lid;
        int col = L >> 5, gs = L & 31;
        int gorig = (gs & 24) | ((gs ^ col) & 7);
        scol[c] = col; goff[c] = gorig * 8; ldsl[c] = L * 8;
    }

    #pragma unroll
    for (int c = 0; c < 4; c++)
        gload_lds16(&et16[(size_t)(cs * 2048 + scol[c]) * 256 + goff[c]], &Bs[0][ldsl[c]]);
    __syncthreads();

    const int swz = m16 & 7;
    for (int tile = 0; tile < 64; tile++) {
        const int cur = tile & 1;
        if (tile + 1 < 64) {
            const int j1 = cs * 2048 + (tile + 1) * 32;
            #pragma unroll
            for (int c = 0; c < 4; c++)
                gload_lds16(&et16[(size_t)(j1 + scol[c]) * 256 + goff[c]],
                            &Bs[cur ^ 1][ldsl[c]]);
        }
        f32x4 a0 = {0.0f, 0.0f, 0.0f, 0.0f}, a1 = a0;
        #pragma unroll
        for (int ks = 0; ks < 8; ks++) {
            const int gq = ks * 4 + g;
            short8 e0 = *(const short8*)&Bs[cur][(m16 * 32 + (gq ^ swz)) * 8];
            short8 e1 = *(const short8*)&Bs[cur][((16 + m16) * 32 + (gq ^ swz)) * 8];
            a0 = mfma16(e0, bfr[ks], a0);
            a1 = mfma16(e1, bfr[ks], a1);
        }
        const unsigned cb = (unsigned)(tile * 32 + g * 4);
        #pragma unroll
        for (int r = 0; r < 4; r++) {
            ins<6>(tk, (fkey(a0[r]) & 0xFFFFF800u) | (cb + (unsigned)r));
            ins<6>(tk, (fkey(a1[r]) & 0xFFFFF800u) | (cb + 16u + (unsigned)r));
        }
        __syncthreads();
    }

    unsigned tk8[8];
    tk8[0] = 0u; tk8[1] = 0u;
    #pragma unroll
    for (int q = 0; q < 6; q++) tk8[q + 2] = tk[q];
    #pragma unroll
    for (int step = 16; step <= 32; step <<= 1) {
        unsigned ok[8];
        #pragma unroll
        for (int q = 0; q < 8; q++) ok[q] = (unsigned)__shfl_xor((int)tk8[q], step);
        #pragma unroll
        for (int q = 0; q < 8; q++) ins<8>(tk8, ok[q]);
    }
    if (g == 0) {
        const int row = r0 + ar + m16;
        #pragma unroll
        for (int q = 0; q < 8; q++)
            candi[(size_t)row * 32 + cs * 8 + q] = cs * 2048 + (int)(tk8[q] & 0x7FFu);
    }
}

// ---------------------------------------------------------------------------
// Stage D (proven R13): LDS-free, barrier-free. 4 waves/block, one row per wave.
// ---------------------------------------------------------------------------
__launch_bounds__(256)
__global__ void stageD(const float* __restrict__ eh, const float* __restrict__ et,
                       const float* __restrict__ rowsum,
                       const int* __restrict__ candi,
                       unsigned short* __restrict__ m1, unsigned short* __restrict__ m2) {
    const int w = threadIdx.x >> 6, l = threadIdx.x & 63;
    const int i = blockIdx.x * 4 + w;

    const int jown = candi[(size_t)i * 32 + (l & 31)] & 8191;

    const int c = l >> 1, h = l & 1;
    const int jc = __shfl(jown, c);
    const float* eprow = &eh[(size_t)i * 256 + h * 128];
    const float* etrow = &et[(size_t)jc * 256 + h * 128];
    double acc = 0.0, acc2 = 0.0;
    #pragma unroll 4
    for (int q = 0; q < 32; q += 2) {
        f32x4 a0 = *(const f32x4*)&eprow[q * 4];
        f32x4 b0 = *(const f32x4*)&etrow[q * 4];
        f32x4 a1 = *(const f32x4*)&eprow[q * 4 + 4];
        f32x4 b1 = *(const f32x4*)&etrow[q * 4 + 4];
        acc  += (double)a0[0] * b0[0] + (double)a0[1] * b0[1] +
                (double)a0[2] * b0[2] + (double)a0[3] * b0[3];
        acc2 += (double)a1[0] * b1[0] + (double)a1[1] * b1[1] +
                (double)a1[2] * b1[2] + (double)a1[3] * b1[3];
    }
    double p = acc + acc2;
    p += __shfl_xor(p, 1);
    p *= 0.0625;

    double v = __shfl(p, 2 * (l & 31));

    float wf[6]; int selj[6];
    #pragma unroll
    for (int s = 0; s < 6; s++) {
        double bv = v; int bj = jown;
        #pragma unroll
        for (int st = 1; st < 64; st <<= 1) {
            double ov = __shfl_xor(bv, st);
            int oj = __shfl_xor(bj, st);
            bool take = (ov > bv) || (ov == bv && oj < bj);
            bv = take ? ov : bv;
            bj = take ? oj : bj;
        }
        wf[s] = (float)bv; selj[s] = bj;
        if (jown == bj) v = -1.0e300;
    }

    float sp[6];
    {
        float mx = wf[0];
        #pragma unroll
        for (int s = 1; s < 6; s++) mx = fmaxf(mx, wf[s]);
        float se = 0.0f, e6[6];
        #pragma unroll
        for (int s = 0; s < 6; s++) { e6[s] = expf(wf[s] - mx); se += e6[s]; }
        #pragma unroll
        for (int s = 0; s < 6; s++) sp[s] = e6[s] / se;
    }

    f32x4 eh4 = *(const f32x4*)&eh[(size_t)i * 256 + l * 4];
    f32x4 nb[6];
    #pragma unroll
    for (int k = 0; k < 6; k++)
        nb[k] = *(const f32x4*)&et[(size_t)selj[k] * 256 + l * 4];

    float pgs[6], pns[6];
    #pragma unroll
    for (int k = 0; k < 6; k++) {
        const float pk = sp[k];
        float pg = 0.0f;
        #pragma unroll
        for (int e = 0; e < 4; e++) {
            float ehd = eh4[e], nbd = nb[k][e];
            float ehr = pk * nbd + (1.0f - pk) * ehd;
            pg += tanhf(ehd + ehr);
        }
        #pragma unroll
        for (int st = 1; st < 64; st <<= 1) pg += __shfl_xor(pg, st);
        pgs[k] = pg;
        pns[k] = rowsum[selj[k]];
    }

    float skp[6];
    {
        float ka[6], mx = -3.0e38f, se = 0.0f;
        #pragma unroll
        for (int k = 0; k < 6; k++) { ka[k] = pns[k] * pgs[k]; mx = fmaxf(mx, ka[k]); }
        #pragma unroll
        for (int k = 0; k < 6; k++) { ka[k] = expf(ka[k] - mx); se += ka[k]; }
        #pragma unroll
        for (int k = 0; k < 6; k++) skp[k] = ka[k] / se;
    }

    f32x4 enh = {0.0f, 0.0f, 0.0f, 0.0f};
    #pragma unroll
    for (int k = 0; k < 6; k++) {
        const float kp = skp[k];
        #pragma unroll
        for (int e = 0; e < 4; e++) enh[e] += kp * nb[k][e];
    }
    short4v h1, h2;
    #pragma unroll
    for (int e = 0; e < 4; e++) {
        h1[e] = (short)f2bf(eh4[e] + enh[e]);
        h2[e] = (short)f2bf(eh4[e] * enh[e]);
    }
    *(short4v*)&m1[(size_t)i * 256 + l * 4] = h1;
    *(short4v*)&m2[(size_t)i * 256 + l * 4] = h2;
}

// ---------------------------------------------------------------------------
__launch_bounds__(256)
__global__ void gate2_k(const float* __restrict__ g1, const float* __restrict__ Ag2,
                        const float* __restrict__ bg2, float* __restrict__ glog) {
    const int i = blockIdx.x * 256 + threadIdx.x;
    float s = 0.0f;
    #pragma unroll 4
    for (int h = 0; h < 128; h++) s += g1[(size_t)i * 128 + h] * Ag2[h];
    glog[i] = s + bg2[0];
}

__launch_bounds__(1024)
__global__ void softmax_g(const float* __restrict__ glog, float* __restrict__ gexp,
                          float* __restrict__ scal) {
    const int t = threadIdx.x;
    __shared__ float red[1024];
    float v[8];
    float m = -3.0e38f;
    #pragma unroll
    for (int c = 0; c < 8; c++) { v[c] = glog[t + c * 1024]; m = fmaxf(m, v[c]); }
    red[t] = m; __syncthreads();
    for (int st = 512; st > 0; st >>= 1) {
        if (t < st) red[t] = fmaxf(red[t], red[t + st]);
        __syncthreads();
    }
    float gm = red[0]; __syncthreads();
    float s = 0.0f;
    #pragma unroll
    for (int c = 0; c < 8; c++) {
        float e = expf(v[c] - gm);
        gexp[t + c * 1024] = e;
        s += e;
    }
    red[t] = s; __syncthreads();
    for (int st = 512; st > 0; st >>= 1) {
        if (t < st) red[t] += red[t + st];
        __syncthreads();
    }
    if (t == 0) scal[0] = 1.0f / red[0];
}

__launch_bounds__(256)
__global__ void wsum_k(const float* __restrict__ emsg, const float* __restrict__ gexp,
                       float* __restrict__ egp) {
    const int b = blockIdx.x, d = threadIdx.x;
    float s = 0.0f;
    const int i0 = b * 128;
    for (int i = 0; i < 128; i++) s += gexp[i0 + i] * emsg[(size_t)(i0 + i) * 256 + d];
    egp[b * 256 + d] = s;
}
__global__ void egfinal_f(const float* __restrict__ egp, const float* __restrict__ scal,
                          float* __restrict__ out) {
    const int d = threadIdx.x;
    float s = 0.0f;
    for (int b = 0; b < 64; b++) s += egp[b * 256 + d];
    out[d] = s * scal[0];
}

__global__ void wsbad_k(float* __restrict__ out) { out[3] = 9000.0f; }

// ---------------------------------------------------------------------------
extern "C" void kernel_launch(void* const* d_in, const int* in_sizes, int n_in,
                              void* d_out, int out_size, void* d_ws, size_t ws_size,
                              hipStream_t stream) {
    (void)in_sizes; (void)n_in; (void)out_size;
    const float* x_path = (const float*)d_in[0];
    const float* fc1_W  = (const float*)d_in[1];
    const float* fc1_b  = (const float*)d_in[2];
    const float* Wh     = (const float*)d_in[3];
    const float* bh     = (const float*)d_in[4];
    const float* Wt     = (const float*)d_in[5];
    const float* bt     = (const float*)d_in[6];
    const float* W1     = (const float*)d_in[7];
    const float* b1     = (const float*)d_in[8];
    const float* W2     = (const float*)d_in[9];
    const float* b2     = (const float*)d_in[10];
    const float* Ag1    = (const float*)d_in[11];
    const float* bg1    = (const float*)d_in[12];
    const float* Ag2    = (const float*)d_in[13];
    const float* bg2    = (const float*)d_in[14];
    float* out_f = (float*)d_out;   // fp32: e_msg [0,2097152), e_g [2097152,2097408)

    const size_t WS_NEEDED = 26412048;
    if (ws_size < WS_NEEDED) {
        hipLaunchKernelGGL(wsbad_k, dim3(1), dim3(1), 0, stream, out_f);
        return;
    }

    char* ws = (char*)d_ws;
    float* x     = (float*)(ws + 0);
    unsigned short* eh16 = (unsigned short*)(ws + 0);
    unsigned short* et16 = (unsigned short*)(ws + 4194304);
    unsigned short* m1b  = (unsigned short*)(ws + 0);
    unsigned short* m2b  = (unsigned short*)(ws + 4194304);
    float* g1    = (float*)(ws + 0);          // 8192x128 fp32 (after m1b/m2b dead)
    float* eh    = (float*)(ws + 8388608);
    float* emsg  = (float*)(ws + 8388608);
    float* et    = (float*)(ws + 16777216);
    int*   candi = (int*)  (ws + 25165824);
    float* rowsum= (float*)(ws + 26214400);   // meanp slot (dead after meanred)
    float* meanp = (float*)(ws + 26214400);
    float* meanv = (float*)(ws + 26279936);
    float* glog  = (float*)(ws + 26280960);
    float* gexp  = (float*)(ws + 26313728);
    float* egp   = (float*)(ws + 26346496);
    float* scal  = (float*)(ws + 26412032);

    // weight planes in temporarily-dead regions (all stream-ordered safe):
    // fc1 planes in et region (et not written until step 3)
    unsigned short* Fp = (unsigned short*)(ws + 16777216);   // 3 x 512 KB
    // Wh/Wt planes in candi region (candi not written until screen2, step 5)
    unsigned short* WHp = (unsigned short*)(ws + 25165824);  // 3 x 128 KB
    unsigned short* WTp = (unsigned short*)(ws + 25559040);  // 3 x 128 KB
    // W1/W2 planes in et region (et dead after stageD, step 6)
    unsigned short* P1 = (unsigned short*)(ws + 16777216);   // 3 x 128 KB
    unsigned short* P2 = (unsigned short*)(ws + 17170432);   // 3 x 128 KB
    // Ag1 planes in candi region (candi dead after stageD)
    unsigned short* Gp = (unsigned short*)(ws + 25165824);   // 3 x 64 KB

    dim3 gg(4, 128);
    // 1) x = leaky(x_path @ fc1_W + fc1_b)  [MFMA 3-split]
    hipLaunchKernelGGL(tsplit3, dim3(8, 32), dim3(256), 0, stream,
                       fc1_W, Fp, 1024, 256, 262144);
    hipLaunchKernelGGL((gemmM<1, 1, 0>), gg, dim3(256), 0, stream,
                       (const void*)x_path, Fp, fc1_b, x, 256, 1024, 262144);
    // 2) x = (x + mean(x)) * 0.5
    hipLaunchKernelGGL(colsum_k, dim3(64), dim3(256), 0, stream, x, meanp);
    hipLaunchKernelGGL(meanred_k, dim3(1), dim3(256), 0, stream, meanp, meanv);
    hipLaunchKernelGGL(finalize_x, dim3(2048), dim3(256), 0, stream, x, meanv);
    // 3) e_h, e_t  [MFMA 3-split, fp32-accurate]
    hipLaunchKernelGGL(tsplit3, dim3(8, 8), dim3(256), 0, stream,
                       Wh, WHp, 256, 256, 65536);
    hipLaunchKernelGGL(tsplit3, dim3(8, 8), dim3(256), 0, stream,
                       Wt, WTp, 256, 256, 65536);
    hipLaunchKernelGGL((gemmM<1, 0, 0>), gg, dim3(256), 0, stream,
                       (const void*)x, WHp, bh, eh, 256, 256, 65536);
    hipLaunchKernelGGL((gemmM<1, 0, 0>), gg, dim3(256), 0, stream,
                       (const void*)x, WTp, bt, et, 256, 256, 65536);
    // 4) bf16 copies for screening + et row sums
    hipLaunchKernelGGL(f2bf_k, dim3(2048), dim3(256), 0, stream, eh, eh16, 524288);
    hipLaunchKernelGGL(f2bf_k, dim3(2048), dim3(256), 0, stream, et, et16, 524288);
    hipLaunchKernelGGL(rowsum_k, dim3(2048), dim3(256), 0, stream, et, rowsum);
    // 5) screening (overwrites Wh/Wt planes with candi -- planes dead)
    hipLaunchKernelGGL(screen2, dim3(4, 128), dim3(256), 0, stream, eh16, et16, candi);
    // 6) fp64 select + message -> m1b/m2b
    hipLaunchKernelGGL(stageD, dim3(2048), dim3(256), 0, stream, eh, et, rowsum,
                       candi, m1b, m2b);
    // 7) e_msg = leaky(m1@W1+b1) + leaky(m2@W2+b2)  [MFMA, A bf16, B 2-plane]
    hipLaunchKernelGGL(tsplit3, dim3(8, 8), dim3(256), 0, stream,
                       W1, P1, 256, 256, 65536);
    hipLaunchKernelGGL(tsplit3, dim3(8, 8), dim3(256), 0, stream,
                       W2, P2, 256, 256, 65536);
    hipLaunchKernelGGL((gemmM<0, 1, 0>), gg, dim3(256), 0, stream,
                       (const void*)m1b, P1, b1, emsg, 256, 256, 65536);
    hipLaunchKernelGGL((gemmM<0, 1, 1>), gg, dim3(256), 0, stream,
                       (const void*)m2b, P2, b2, emsg, 256, 256, 65536);
    // 8) output 0: e_msg fp32
    hipLaunchKernelGGL(cpy_k, dim3(2048), dim3(256), 0, stream, emsg, out_f);
    // 9) readout: g1 = leaky(emsg@Ag1+bg1) [MFMA 3-split]; then small ops
    hipLaunchKernelGGL(tsplit3, dim3(4, 8), dim3(256), 0, stream,
                       Ag1, Gp, 256, 128, 32768);
    hipLaunchKernelGGL((gemmM<1, 1, 0>), dim3(2, 128), dim3(256), 0, stream,
                       (const void*)emsg, Gp, bg1, g1, 128, 256, 32768);
    hipLaunchKernelGGL(gate2_k, dim3(32), dim3(256), 0, stream, g1, Ag2, bg2, glog);
    hipLaunchKernelGGL(softmax_g, dim3(1), dim3(1024), 0, stream, glog, gexp, scal);
    hipLaunchKernelGGL(wsum_k, dim3(64), dim3(256), 0, stream, emsg, gexp, egp);
    hipLaunchKernelGGL(egfinal_f, dim3(1), dim3(256), 0, stream, egp, scal, out_f + 2097152);
}

// Round 6
// 362.482 us; speedup vs baseline: 1.5160x; 1.0408x over previous
//
#include <hip/hip_runtime.h>

// MOTCAT_Surv R16. R15 passed (absmax 0.0156, 377 us); screen2 back on top (77 us,
// MfmaUtil 17.7%, VALUBusy 51%, conflicts 8.4e6). Per-CU accounting: each wave reads
// the full 16KB et tile to score only 16 rows -> LDS pipe (1536 cyc/tile/CU) is the
// wall. This round: (a) 32 rows/wave (2 register B-frag sets; reads + MFMA verbatim
// R12 doubled over the row-set) -> LDS volume per output HALVES; block = 128 rows,
// grid (4,64) = 1 wg/CU; (b) float-key top-k with v_med3_f32 insert (1 op/slot,
// no fkey transform) -> top-k VALU halves; col bits live in the low-11 mantissa
// (ordering-equivalent; negative-tie flips toward larger col -- both legitimate
// superset members, stageD rescores fp64); (c) emsg := out_f directly (cpy_k
// deleted; step-7 gemms write d_out, gate/wsum read it). Everything else = R15.

typedef __attribute__((ext_vector_type(8))) short short8;
typedef __attribute__((ext_vector_type(4))) short short4v;
typedef __attribute__((ext_vector_type(4))) float f32x4;

__device__ inline float bf2f(unsigned short b) {
    unsigned u = ((unsigned)b) << 16;
    return __builtin_bit_cast(float, u);
}
__device__ inline unsigned short f2bf(float f) {   // round-to-nearest-even
    unsigned u = __builtin_bit_cast(unsigned, f);
    unsigned r = u + 0x7fffu + ((u >> 16) & 1u);
    return (unsigned short)(r >> 16);
}
__device__ inline f32x4 mfma16(short8 a, short8 b, f32x4 c) {
    return __builtin_amdgcn_mfma_f32_16x16x32_bf16(a, b, c, 0, 0, 0);
}
// A-frag: lane holds A[m=lane&15][k=(lane>>4)*8+j]; B-frag: B[k][n=lane&15];
// C/D: col=lane&15 (n), row=(lane>>4)*4+reg (m) (learn_hip m89).

__device__ inline void gload_lds16(const unsigned short* g, unsigned short* l) {
    __builtin_amdgcn_global_load_lds(
        (const __attribute__((address_space(1))) void*)g,
        (__attribute__((address_space(3))) void*)l, 16, 0, 0);
}

// split fp32 -> bf16 hi/mid/lo (residual subtractions are exact: operands close)
__device__ inline void split8(const f32x4 v0, const f32x4 v1,
                              short8& hi, short8& md, short8& lo) {
    #pragma unroll
    for (int e = 0; e < 8; e++) {
        float a = (e < 4) ? v0[e] : v1[e - 4];
        unsigned short h = f2bf(a);
        float r1 = a - bf2f(h);
        unsigned short m = f2bf(r1);
        float r2 = r1 - bf2f(m);
        unsigned short l = f2bf(r2);
        hi[e] = (short)h; md[e] = (short)m; lo[e] = (short)l;
    }
}

// ---------------------------------------------------------------------------
// tsplit3: W [K][N] fp32 -> Bt planes [n][k] bf16 (hi, mid, lo) at out + p*PS.
// ---------------------------------------------------------------------------
__launch_bounds__(256)
__global__ void tsplit3(const float* __restrict__ W, unsigned short* __restrict__ out,
                        int K, int N, int PS) {
    __shared__ float T[32][33];
    const int t = threadIdx.x;
    const int n0 = blockIdx.x * 32, k0 = blockIdx.y * 32;
    {
        const int r = t >> 3, c = (t & 7) * 4;
        f32x4 v = *(const f32x4*)&W[(size_t)(k0 + r) * N + n0 + c];
        #pragma unroll
        for (int e = 0; e < 4; e++) T[r][c + e] = v[e];
    }
    __syncthreads();
    const int nr = t >> 3, kc = (t & 7) * 4;
    short4v h4, m4, l4;
    #pragma unroll
    for (int e = 0; e < 4; e++) {
        float a = T[kc + e][nr];
        unsigned short h = f2bf(a);
        float r1 = a - bf2f(h);
        unsigned short m = f2bf(r1);
        float r2 = r1 - bf2f(m);
        h4[e] = (short)h; m4[e] = (short)m; l4[e] = (short)f2bf(r2);
    }
    const size_t o = (size_t)(n0 + nr) * K + k0 + kc;
    *(short4v*)&out[o] = h4;
    *(short4v*)&out[(size_t)PS + o] = m4;
    *(short4v*)&out[(size_t)2 * PS + o] = l4;
}

// ---------------------------------------------------------------------------
// gemmM (proven R15): C = act(A@B + bias) (+=C if ACCUM) on matrix cores.
// ---------------------------------------------------------------------------
template <int ASPLIT, int ACT, int ACCUM>
__launch_bounds__(256)
__global__ void gemmM(const void* __restrict__ Av,
                      const unsigned short* __restrict__ Bt,
                      const float* __restrict__ bias, float* __restrict__ C,
                      int N, int K, int BPS) {
    constexpr int APL = ASPLIT ? 3 : 1;
    constexpr int BPL = ASPLIT ? 3 : 2;
    __shared__ __align__(16) unsigned short LA[2][APL * 2048];
    __shared__ __align__(16) unsigned short LB[2][BPL * 2048];
    const int t = threadIdx.x;
    const int r0 = blockIdx.y * 64, c0 = blockIdx.x * 64;
    const int lid = t & 63, w = t >> 6, g = lid >> 4, m16 = lid & 15;
    const int wm = w >> 1, wn = w & 1;

    f32x4 acc[2][2];
    #pragma unroll
    for (int mf = 0; mf < 2; mf++)
        #pragma unroll
        for (int nf = 0; nf < 2; nf++) acc[mf][nf] = {0.0f, 0.0f, 0.0f, 0.0f};

    const int KT = K >> 5;
    const size_t aoff = (size_t)(r0 + (t >> 2)) * K + (t & 3) * 8;
    const size_t boff = (size_t)(c0 + (t >> 2)) * K + (t & 3) * 8;

    {
        #pragma unroll
        for (int p = 0; p < BPL; p++)
            gload_lds16(&Bt[(size_t)p * BPS + boff], &LB[0][p * 2048 + 8 * t]);
        if (ASPLIT) {
            const float* A = (const float*)Av;
            f32x4 v0 = *(const f32x4*)&A[aoff];
            f32x4 v1 = *(const f32x4*)&A[aoff + 4];
            short8 hi, md, lo;
            split8(v0, v1, hi, md, lo);
            *(short8*)&LA[0][8 * t] = hi;
            *(short8*)&LA[0][2048 + 8 * t] = md;
            *(short8*)&LA[0][4096 + 8 * t] = lo;
        } else {
            const unsigned short* A16 = (const unsigned short*)Av;
            gload_lds16(&A16[aoff], &LA[0][8 * t]);
        }
    }
    __syncthreads();

    for (int kt = 0; kt < KT; kt++) {
        const int cur = kt & 1, nxt = cur ^ 1;
        const bool hn = (kt + 1) < KT;
        f32x4 v0, v1;
        if (hn) {
            const size_t ko = (size_t)(kt + 1) * 32;
            #pragma unroll
            for (int p = 0; p < BPL; p++)
                gload_lds16(&Bt[(size_t)p * BPS + boff + ko],
                            &LB[nxt][p * 2048 + 8 * t]);
            if (ASPLIT) {
                const float* A = (const float*)Av;
                v0 = *(const f32x4*)&A[aoff + ko];
                v1 = *(const f32x4*)&A[aoff + ko + 4];
            } else {
                const unsigned short* A16 = (const unsigned short*)Av;
                gload_lds16(&A16[aoff + ko], &LA[nxt][8 * t]);
            }
        }
        short8 af[2][APL], bf[2][BPL];
        #pragma unroll
        for (int mf = 0; mf < 2; mf++) {
            const int row = wm * 32 + mf * 16 + m16;
            #pragma unroll
            for (int p = 0; p < APL; p++)
                af[mf][p] = *(const short8*)&LA[cur][p * 2048 + row * 32 + g * 8];
        }
        #pragma unroll
        for (int nf = 0; nf < 2; nf++) {
            const int col = wn * 32 + nf * 16 + m16;
            #pragma unroll
            for (int p = 0; p < BPL; p++)
                bf[nf][p] = *(const short8*)&LB[cur][p * 2048 + col * 32 + g * 8];
        }
        #pragma unroll
        for (int mf = 0; mf < 2; mf++)
            #pragma unroll
            for (int nf = 0; nf < 2; nf++) {
                if (ASPLIT) {
                    acc[mf][nf] = mfma16(af[mf][0], bf[nf][0], acc[mf][nf]); // hh
                    acc[mf][nf] = mfma16(af[mf][0], bf[nf][1], acc[mf][nf]); // hm
                    acc[mf][nf] = mfma16(af[mf][1], bf[nf][0], acc[mf][nf]); // mh
                    acc[mf][nf] = mfma16(af[mf][0], bf[nf][2], acc[mf][nf]); // hl
                    acc[mf][nf] = mfma16(af[mf][1], bf[nf][1], acc[mf][nf]); // mm
                    acc[mf][nf] = mfma16(af[mf][2], bf[nf][0], acc[mf][nf]); // lh
                } else {
                    acc[mf][nf] = mfma16(af[mf][0], bf[nf][0], acc[mf][nf]);
                    acc[mf][nf] = mfma16(af[mf][0], bf[nf][1], acc[mf][nf]);
                }
            }
        if (hn && ASPLIT) {
            short8 hi, md, lo;
            split8(v0, v1, hi, md, lo);
            *(short8*)&LA[nxt][8 * t] = hi;
            *(short8*)&LA[nxt][2048 + 8 * t] = md;
            *(short8*)&LA[nxt][4096 + 8 * t] = lo;
        }
        __syncthreads();
    }

    #pragma unroll
    for (int nf = 0; nf < 2; nf++) {
        const int col = c0 + wn * 32 + nf * 16 + m16;
        const float bv = bias[col];
        #pragma unroll
        for (int mf = 0; mf < 2; mf++) {
            #pragma unroll
            for (int r = 0; r < 4; r++) {
                const int row = r0 + wm * 32 + mf * 16 + g * 4 + r;
                float v = acc[mf][nf][r] + bv;
                if (ACT == 1) v = v > 0.0f ? v : 0.01f * v;
                size_t idx = (size_t)row * N + col;
                if (ACCUM) v += C[idx];
                C[idx] = v;
            }
        }
    }
}

// ---------------------------------------------------------------------------
__global__ void colsum_k(const float* __restrict__ x, float* __restrict__ out) {
    int d = threadIdx.x, b = blockIdx.x;
    float s = 0.0f;
    int i0 = b * 128;
    for (int i = 0; i < 128; i++) s += x[(size_t)(i0 + i) * 256 + d];
    out[b * 256 + d] = s;
}
__global__ void meanred_k(const float* __restrict__ p, float* __restrict__ mean) {
    int d = threadIdx.x;
    float s = 0.0f;
    for (int b = 0; b < 64; b++) s += p[b * 256 + d];
    mean[d] = s * (1.0f / 8192.0f);
}
__global__ void finalize_x(float* __restrict__ x, const float* __restrict__ mean) {
    size_t idx = (size_t)blockIdx.x * blockDim.x + threadIdx.x;
    f32x4 v = *(f32x4*)&x[idx * 4];
    int d4 = (int)((idx * 4) & 255);
    f32x4 m = *(const f32x4*)&mean[d4];
    #pragma unroll
    for (int e = 0; e < 4; e++) v[e] = (v[e] + m[e]) * 0.5f;
    *(f32x4*)&x[idx * 4] = v;
}
__global__ void f2bf_k(const float* __restrict__ src, unsigned short* __restrict__ dst, int n4) {
    size_t idx = (size_t)blockIdx.x * blockDim.x + threadIdx.x;
    if (idx >= (size_t)n4) return;
    f32x4 v = *(const f32x4*)&src[idx * 4];
    short4v h;
    #pragma unroll
    for (int e = 0; e < 4; e++) h[e] = (short)f2bf(v[e]);
    *(short4v*)&dst[idx * 4] = h;
}
// rowsum[i] = sum_d et[i][d]
__launch_bounds__(256)
__global__ void rowsum_k(const float* __restrict__ et, float* __restrict__ rowsum) {
    const int w = threadIdx.x >> 6, l = threadIdx.x & 63;
    const int i = blockIdx.x * 4 + w;
    f32x4 v = *(const f32x4*)&et[(size_t)i * 256 + l * 4];
    float s = v[0] + v[1] + v[2] + v[3];
    #pragma unroll
    for (int st = 1; st < 64; st <<= 1) s += __shfl_xor(s, st);
    if (l == 0) rowsum[i] = s;
}

// ---------------------------------------------------------------------------
// screen2 R16 helpers: float keys (col in low-11 mantissa bits), med3 insert.
// Sorted ascending, tk[0]=min. tk[k] = med3(key, tk[k+1], tk[k]) == clamp since
// tk[k] <= tk[k+1]; iter k reads OLD tk[k+1] (same semantics as uint version).
// ---------------------------------------------------------------------------
__device__ inline float packkey(float v, unsigned col) {
    unsigned u = (__builtin_bit_cast(unsigned, v) & 0xFFFFF800u) | col;
    return __builtin_bit_cast(float, u);
}
template<int NK>
__device__ inline void insf(float (&tk)[NK], float key) {
    #pragma unroll
    for (int k = 0; k < NK - 1; k++)
        tk[k] = __builtin_amdgcn_fmed3f(key, tk[k + 1], tk[k]);
    tk[NK - 1] = fmaxf(tk[NK - 1], key);
}

// ---------------------------------------------------------------------------
// screen2 R16: 32 eh rows per wave (2 B-frag sets), 128 rows/block, grid (4,64).
// Per tile: 16 ds_read_b128 (XOR-swizzled, verbatim R12) feed 32 MFMA (2 row-
// sets x R12's 16). Lane (g,m16) scores rows {r0+w*32+m16, +16} x cols
// tile*32 + {g*4+r, 16+g*4+r}. Two float top-6 queues/lane (med3 insert),
// 2-step butterfly merge over g -> top-8/quarter/row.
// ---------------------------------------------------------------------------
__launch_bounds__(256)
__global__ void screen2(const unsigned short* __restrict__ eh16,
                        const unsigned short* __restrict__ et16,
                        int* __restrict__ candi) {
    __shared__ __align__(16) unsigned short Bs[2][8192];   // 2 x (32 cols x 256 k)
    const int t = threadIdx.x;
    const int cs = blockIdx.x;
    const int r0 = blockIdx.y * 128;
    const int w = t >> 6, lid = t & 63, g = lid >> 4, m16 = lid & 15;

    short8 bfr[2][8];   // eh B-frags: rows r0+w*32+s*16+m16, k = ks*32 + g*8 + j
    #pragma unroll
    for (int s = 0; s < 2; s++)
        #pragma unroll
        for (int ks = 0; ks < 8; ks++)
            bfr[s][ks] = *(const short8*)
                &eh16[(size_t)(r0 + w * 32 + s * 16 + m16) * 256 + ks * 32 + g * 8];

    float tk0[6], tk1[6];
    #pragma unroll
    for (int q = 0; q < 6; q++) { tk0[q] = -3.0e38f; tk1[q] = -3.0e38f; }

    // staging map (verbatim R12): chunk = w*4+c; linear LDS granule L holds
    // (col = L>>5, gorig = (gs&24)|((gs^col)&7)), gs = L&31.
    int scol[4], goff[4], ldsl[4];
    #pragma unroll
    for (int c = 0; c < 4; c++) {
        int L = (w * 4 + c) * 64 + lid;
        int col = L >> 5, gs = L & 31;
        int gorig = (gs & 24) | ((gs ^ col) & 7);
        scol[c] = col; goff[c] = gorig * 8; ldsl[c] = L * 8;
    }

    #pragma unroll
    for (int c = 0; c < 4; c++)
        gload_lds16(&et16[(size_t)(cs * 2048 + scol[c]) * 256 + goff[c]], &Bs[0][ldsl[c]]);
    __syncthreads();

    const int swz = m16 & 7;
    for (int tile = 0; tile < 64; tile++) {
        const int cur = tile & 1;
        if (tile + 1 < 64) {
            const int j1 = cs * 2048 + (tile + 1) * 32;
            #pragma unroll
            for (int c = 0; c < 4; c++)
                gload_lds16(&et16[(size_t)(j1 + scol[c]) * 256 + goff[c]],
                            &Bs[cur ^ 1][ldsl[c]]);
        }
        f32x4 a00 = {0.0f, 0.0f, 0.0f, 0.0f}, a01 = a00, a10 = a00, a11 = a00;
        #pragma unroll
        for (int ks = 0; ks < 8; ks++) {
            const int gq = ks * 4 + g;
            short8 e0 = *(const short8*)&Bs[cur][(m16 * 32 + (gq ^ swz)) * 8];
            short8 e1 = *(const short8*)&Bs[cur][((16 + m16) * 32 + (gq ^ swz)) * 8];
            a00 = mfma16(e0, bfr[0][ks], a00);   // A = et (LDS), B = eh (regs)
            a01 = mfma16(e1, bfr[0][ks], a01);
            a10 = mfma16(e0, bfr[1][ks], a10);
            a11 = mfma16(e1, bfr[1][ks], a11);
        }
        const unsigned cb = (unsigned)(tile * 32 + g * 4);
        #pragma unroll
        for (int r = 0; r < 4; r++) {
            insf<6>(tk0, packkey(a00[r], cb + (unsigned)r));
            insf<6>(tk0, packkey(a01[r], cb + 16u + (unsigned)r));
            insf<6>(tk1, packkey(a10[r], cb + (unsigned)r));
            insf<6>(tk1, packkey(a11[r], cb + 16u + (unsigned)r));
        }
        __syncthreads();
    }

    // per row-set: widen to 8 (sentinels), butterfly-merge over the 4 g-lanes
    #pragma unroll
    for (int s = 0; s < 2; s++) {
        float tk8[8];
        tk8[0] = -3.0e38f; tk8[1] = -3.0e38f;
        #pragma unroll
        for (int q = 0; q < 6; q++) tk8[q + 2] = s ? tk1[q] : tk0[q];
        #pragma unroll
        for (int step = 16; step <= 32; step <<= 1) {
            float ok[8];
            #pragma unroll
            for (int q = 0; q < 8; q++) ok[q] = __shfl_xor(tk8[q], step);
            #pragma unroll
            for (int q = 0; q < 8; q++) insf<8>(tk8, ok[q]);
        }
        if (g == 0) {
            const int row = r0 + w * 32 + s * 16 + m16;
            #pragma unroll
            for (int q = 0; q < 8; q++)
                candi[(size_t)row * 32 + cs * 8 + q] =
                    cs * 2048 + (int)(__builtin_bit_cast(unsigned, tk8[q]) & 0x7FFu);
        }
    }
}

// ---------------------------------------------------------------------------
// Stage D (proven R13): LDS-free, barrier-free. 4 waves/block, one row per wave.
// ---------------------------------------------------------------------------
__launch_bounds__(256)
__global__ void stageD(const float* __restrict__ eh, const float* __restrict__ et,
                       const float* __restrict__ rowsum,
                       const int* __restrict__ candi,
                       unsigned short* __restrict__ m1, unsigned short* __restrict__ m2) {
    const int w = threadIdx.x >> 6, l = threadIdx.x & 63;
    const int i = blockIdx.x * 4 + w;

    const int jown = candi[(size_t)i * 32 + (l & 31)] & 8191;

    const int c = l >> 1, h = l & 1;
    const int jc = __shfl(jown, c);
    const float* eprow = &eh[(size_t)i * 256 + h * 128];
    const float* etrow = &et[(size_t)jc * 256 + h * 128];
    double acc = 0.0, acc2 = 0.0;
    #pragma unroll 4
    for (int q = 0; q < 32; q += 2) {
        f32x4 a0 = *(const f32x4*)&eprow[q * 4];
        f32x4 b0 = *(const f32x4*)&etrow[q * 4];
        f32x4 a1 = *(const f32x4*)&eprow[q * 4 + 4];
        f32x4 b1 = *(const f32x4*)&etrow[q * 4 + 4];
        acc  += (double)a0[0] * b0[0] + (double)a0[1] * b0[1] +
                (double)a0[2] * b0[2] + (double)a0[3] * b0[3];
        acc2 += (double)a1[0] * b1[0] + (double)a1[1] * b1[1] +
                (double)a1[2] * b1[2] + (double)a1[3] * b1[3];
    }
    double p = acc + acc2;
    p += __shfl_xor(p, 1);
    p *= 0.0625;

    double v = __shfl(p, 2 * (l & 31));

    float wf[6]; int selj[6];
    #pragma unroll
    for (int s = 0; s < 6; s++) {
        double bv = v; int bj = jown;
        #pragma unroll
        for (int st = 1; st < 64; st <<= 1) {
            double ov = __shfl_xor(bv, st);
            int oj = __shfl_xor(bj, st);
            bool take = (ov > bv) || (ov == bv && oj < bj);
            bv = take ? ov : bv;
            bj = take ? oj : bj;
        }
        wf[s] = (float)bv; selj[s] = bj;
        if (jown == bj) v = -1.0e300;
    }

    float sp[6];
    {
        float mx = wf[0];
        #pragma unroll
        for (int s = 1; s < 6; s++) mx = fmaxf(mx, wf[s]);
        float se = 0.0f, e6[6];
        #pragma unroll
        for (int s = 0; s < 6; s++) { e6[s] = expf(wf[s] - mx); se += e6[s]; }
        #pragma unroll
        for (int s = 0; s < 6; s++) sp[s] = e6[s] / se;
    }

    f32x4 eh4 = *(const f32x4*)&eh[(size_t)i * 256 + l * 4];
    f32x4 nb[6];
    #pragma unroll
    for (int k = 0; k < 6; k++)
        nb[k] = *(const f32x4*)&et[(size_t)selj[k] * 256 + l * 4];

    float pgs[6], pns[6];
    #pragma unroll
    for (int k = 0; k < 6; k++) {
        const float pk = sp[k];
        float pg = 0.0f;
        #pragma unroll
        for (int e = 0; e < 4; e++) {
            float ehd = eh4[e], nbd = nb[k][e];
            float ehr = pk * nbd + (1.0f - pk) * ehd;
            pg += tanhf(ehd + ehr);
        }
        #pragma unroll
        for (int st = 1; st < 64; st <<= 1) pg += __shfl_xor(pg, st);
        pgs[k] = pg;
        pns[k] = rowsum[selj[k]];
    }

    float skp[6];
    {
        float ka[6], mx = -3.0e38f, se = 0.0f;
        #pragma unroll
        for (int k = 0; k < 6; k++) { ka[k] = pns[k] * pgs[k]; mx = fmaxf(mx, ka[k]); }
        #pragma unroll
        for (int k = 0; k < 6; k++) { ka[k] = expf(ka[k] - mx); se += ka[k]; }
        #pragma unroll
        for (int k = 0; k < 6; k++) skp[k] = ka[k] / se;
    }

    f32x4 enh = {0.0f, 0.0f, 0.0f, 0.0f};
    #pragma unroll
    for (int k = 0; k < 6; k++) {
        const float kp = skp[k];
        #pragma unroll
        for (int e = 0; e < 4; e++) enh[e] += kp * nb[k][e];
    }
    short4v h1, h2;
    #pragma unroll
    for (int e = 0; e < 4; e++) {
        h1[e] = (short)f2bf(eh4[e] + enh[e]);
        h2[e] = (short)f2bf(eh4[e] * enh[e]);
    }
    *(short4v*)&m1[(size_t)i * 256 + l * 4] = h1;
    *(short4v*)&m2[(size_t)i * 256 + l * 4] = h2;
}

// ---------------------------------------------------------------------------
__launch_bounds__(256)
__global__ void gate2_k(const float* __restrict__ g1, const float* __restrict__ Ag2,
                        const float* __restrict__ bg2, float* __restrict__ glog) {
    const int i = blockIdx.x * 256 + threadIdx.x;
    float s = 0.0f;
    #pragma unroll 4
    for (int h = 0; h < 128; h++) s += g1[(size_t)i * 128 + h] * Ag2[h];
    glog[i] = s + bg2[0];
}

__launch_bounds__(1024)
__global__ void softmax_g(const float* __restrict__ glog, float* __restrict__ gexp,
                          float* __restrict__ scal) {
    const int t = threadIdx.x;
    __shared__ float red[1024];
    float v[8];
    float m = -3.0e38f;
    #pragma unroll
    for (int c = 0; c < 8; c++) { v[c] = glog[t + c * 1024]; m = fmaxf(m, v[c]); }
    red[t] = m; __syncthreads();
    for (int st = 512; st > 0; st >>= 1) {
        if (t < st) red[t] = fmaxf(red[t], red[t + st]);
        __syncthreads();
    }
    float gm = red[0]; __syncthreads();
    float s = 0.0f;
    #pragma unroll
    for (int c = 0; c < 8; c++) {
        float e = expf(v[c] - gm);
        gexp[t + c * 1024] = e;
        s += e;
    }
    red[t] = s; __syncthreads();
    for (int st = 512; st > 0; st >>= 1) {
        if (t < st) red[t] += red[t + st];
        __syncthreads();
    }
    if (t == 0) scal[0] = 1.0f / red[0];
}

__launch_bounds__(256)
__global__ void wsum_k(const float* __restrict__ emsg, const float* __restrict__ gexp,
                       float* __restrict__ egp) {
    const int b = blockIdx.x, d = threadIdx.x;
    float s = 0.0f;
    const int i0 = b * 128;
    for (int i = 0; i < 128; i++) s += gexp[i0 + i] * emsg[(size_t)(i0 + i) * 256 + d];
    egp[b * 256 + d] = s;
}
__global__ void egfinal_f(const float* __restrict__ egp, const float* __restrict__ scal,
                          float* __restrict__ out) {
    const int d = threadIdx.x;
    float s = 0.0f;
    for (int b = 0; b < 64; b++) s += egp[b * 256 + d];
    out[d] = s * scal[0];
}

__global__ void wsbad_k(float* __restrict__ out) { out[3] = 9000.0f; }

// ---------------------------------------------------------------------------
extern "C" void kernel_launch(void* const* d_in, const int* in_sizes, int n_in,
                              void* d_out, int out_size, void* d_ws, size_t ws_size,
                              hipStream_t stream) {
    (void)in_sizes; (void)n_in; (void)out_size;
    const float* x_path = (const float*)d_in[0];
    const float* fc1_W  = (const float*)d_in[1];
    const float* fc1_b  = (const float*)d_in[2];
    const float* Wh     = (const float*)d_in[3];
    const float* bh     = (const float*)d_in[4];
    const float* Wt     = (const float*)d_in[5];
    const float* bt     = (const float*)d_in[6];
    const float* W1     = (const float*)d_in[7];
    const float* b1     = (const float*)d_in[8];
    const float* W2     = (const float*)d_in[9];
    const float* b2     = (const float*)d_in[10];
    const float* Ag1    = (const float*)d_in[11];
    const float* bg1    = (const float*)d_in[12];
    const float* Ag2    = (const float*)d_in[13];
    const float* bg2    = (const float*)d_in[14];
    float* out_f = (float*)d_out;   // fp32: e_msg [0,2097152), e_g [2097152,2097408)

    const size_t WS_NEEDED = 26412048;
    if (ws_size < WS_NEEDED) {
        hipLaunchKernelGGL(wsbad_k, dim3(1), dim3(1), 0, stream, out_f);
        return;
    }

    char* ws = (char*)d_ws;
    float* x     = (float*)(ws + 0);
    unsigned short* eh16 = (unsigned short*)(ws + 0);
    unsigned short* et16 = (unsigned short*)(ws + 4194304);
    unsigned short* m1b  = (unsigned short*)(ws + 0);
    unsigned short* m2b  = (unsigned short*)(ws + 4194304);
    float* g1    = (float*)(ws + 0);          // 8192x128 fp32 (after m1b/m2b dead)
    float* eh    = (float*)(ws + 8388608);
    float* emsg  = out_f;                     // e_msg written straight to d_out
    float* et    = (float*)(ws + 16777216);
    int*   candi = (int*)  (ws + 25165824);
    float* rowsum= (float*)(ws + 26214400);   // meanp slot (dead after meanred)
    float* meanp = (float*)(ws + 26214400);
    float* meanv = (float*)(ws + 26279936);
    float* glog  = (float*)(ws + 26280960);
    float* gexp  = (float*)(ws + 26313728);
    float* egp   = (float*)(ws + 26346496);
    float* scal  = (float*)(ws + 26412032);

    // weight planes in temporarily-dead regions (all stream-ordered safe):
    unsigned short* Fp = (unsigned short*)(ws + 16777216);   // fc1, in et region
    unsigned short* WHp = (unsigned short*)(ws + 25165824);  // in candi region
    unsigned short* WTp = (unsigned short*)(ws + 25559040);
    unsigned short* P1 = (unsigned short*)(ws + 16777216);   // in et region (post-stageD)
    unsigned short* P2 = (unsigned short*)(ws + 17170432);
    unsigned short* Gp = (unsigned short*)(ws + 25165824);   // in candi region (post-stageD)

    dim3 gg(4, 128);
    // 1) x = leaky(x_path @ fc1_W + fc1_b)  [MFMA 3-split]
    hipLaunchKernelGGL(tsplit3, dim3(8, 32), dim3(256), 0, stream,
                       fc1_W, Fp, 1024, 256, 262144);
    hipLaunchKernelGGL((gemmM<1, 1, 0>), gg, dim3(256), 0, stream,
                       (const void*)x_path, Fp, fc1_b, x, 256, 1024, 262144);
    // 2) x = (x + mean(x)) * 0.5
    hipLaunchKernelGGL(colsum_k, dim3(64), dim3(256), 0, stream, x, meanp);
    hipLaunchKernelGGL(meanred_k, dim3(1), dim3(256), 0, stream, meanp, meanv);
    hipLaunchKernelGGL(finalize_x, dim3(2048), dim3(256), 0, stream, x, meanv);
    // 3) e_h, e_t  [MFMA 3-split, fp32-accurate]
    hipLaunchKernelGGL(tsplit3, dim3(8, 8), dim3(256), 0, stream,
                       Wh, WHp, 256, 256, 65536);
    hipLaunchKernelGGL(tsplit3, dim3(8, 8), dim3(256), 0, stream,
                       Wt, WTp, 256, 256, 65536);
    hipLaunchKernelGGL((gemmM<1, 0, 0>), gg, dim3(256), 0, stream,
                       (const void*)x, WHp, bh, eh, 256, 256, 65536);
    hipLaunchKernelGGL((gemmM<1, 0, 0>), gg, dim3(256), 0, stream,
                       (const void*)x, WTp, bt, et, 256, 256, 65536);
    // 4) bf16 copies for screening + et row sums
    hipLaunchKernelGGL(f2bf_k, dim3(2048), dim3(256), 0, stream, eh, eh16, 524288);
    hipLaunchKernelGGL(f2bf_k, dim3(2048), dim3(256), 0, stream, et, et16, 524288);
    hipLaunchKernelGGL(rowsum_k, dim3(2048), dim3(256), 0, stream, et, rowsum);
    // 5) screening: 32 rows/wave, top-6/lane med3 -> top-8/quarter -> 32 cand/row
    hipLaunchKernelGGL(screen2, dim3(4, 64), dim3(256), 0, stream, eh16, et16, candi);
    // 6) fp64 select + message -> m1b/m2b
    hipLaunchKernelGGL(stageD, dim3(2048), dim3(256), 0, stream, eh, et, rowsum,
                       candi, m1b, m2b);
    // 7) e_msg = leaky(m1@W1+b1) + leaky(m2@W2+b2)  -> straight into out_f
    hipLaunchKernelGGL(tsplit3, dim3(8, 8), dim3(256), 0, stream,
                       W1, P1, 256, 256, 65536);
    hipLaunchKernelGGL(tsplit3, dim3(8, 8), dim3(256), 0, stream,
                       W2, P2, 256, 256, 65536);
    hipLaunchKernelGGL((gemmM<0, 1, 0>), gg, dim3(256), 0, stream,
                       (const void*)m1b, P1, b1, emsg, 256, 256, 65536);
    hipLaunchKernelGGL((gemmM<0, 1, 1>), gg, dim3(256), 0, stream,
                       (const void*)m2b, P2, b2, emsg, 256, 256, 65536);
    // 8) readout: g1 = leaky(emsg@Ag1+bg1) [MFMA 3-split]; then small ops
    hipLaunchKernelGGL(tsplit3, dim3(4, 8), dim3(256), 0, stream,
                       Ag1, Gp, 256, 128, 32768);
    hipLaunchKernelGGL((gemmM<1, 1, 0>), dim3(2, 128), dim3(256), 0, stream,
                       (const void*)emsg, Gp, bg1, g1, 128, 256, 32768);
    hipLaunchKernelGGL(gate2_k, dim3(32), dim3(256), 0, stream, g1, Ag2, bg2, glog);
    hipLaunchKernelGGL(softmax_g, dim3(1), dim3(1024), 0, stream, glog, gexp, scal);
    hipLaunchKernelGGL(wsum_k, dim3(64), dim3(256), 0, stream, emsg, gexp, egp);
    hipLaunchKernelGGL(egfinal_f, dim3(1), dim3(256), 0, stream, egp, scal, out_f + 2097152);
}